// Round 1
// baseline (245.225 us; speedup 1.0000x reference)
//
#include <hip/hip_runtime.h>

// Problem constants (fixed by reference)
#define BB 16
#define SS 1024
#define NIN 7
#define NHID 28
#define NH 7
#define DH 4

// Raw 2^x (v_exp_f32). NOTE: __exp2f does NOT exist in HIP device code
// (R7 compile failure -- glibc math.h macro collision). exp(x) == exp2(x*log2e);
// the log2e factor is folded into the Q / Q2 projection scales.
#define EXP2F(x) __builtin_amdgcn_exp2f(x)

constexpr int ROWS = BB * SS;                 // 16384
constexpr int QKV_ELEMS = BB * NH * SS * DH;  // 458752 floats per tensor

// ---------------------------------------------------------------------------
// Kernel 1: QKV projection. inputs [B,S,7] @ W[7,28] + b -> Q,K,V in
// head-major layout [B][H][S][4]. Q pre-scaled by (1/sqrt(DH)) * log2(e)
// so attention-1 can use exp2 instead of exp (saves one v_mul per pair).
// ---------------------------------------------------------------------------
__global__ __launch_bounds__(256) void k_proj(
    const float* __restrict__ inp,
    const float* __restrict__ Wq, const float* __restrict__ bq,
    const float* __restrict__ Wk, const float* __restrict__ bk,
    const float* __restrict__ Wv, const float* __restrict__ bv,
    float* __restrict__ Qo, float* __restrict__ Ko, float* __restrict__ Vo)
{
    __shared__ float  xs[256 * NIN];   // 7 KB: 256 rows of inputs
    __shared__ float4 w4[147];         // Wq(49) | Wk(49) | Wv(49) as float4
    __shared__ float4 b4[21];          // bq(7) | bk(7) | bv(7)

    const int tid  = threadIdx.x;
    const int row0 = blockIdx.x * 256;

    #pragma unroll
    for (int i = 0; i < NIN; ++i) xs[tid + 256 * i] = inp[row0 * NIN + tid + 256 * i];

    if (tid < 147) {
        const float* src = (tid < 49) ? Wq : (tid < 98) ? Wk : Wv;
        int off = (tid < 49) ? tid : (tid < 98) ? tid - 49 : tid - 98;
        w4[tid] = ((const float4*)src)[off];
    } else if (tid < 168) {
        int t = tid - 147;
        const float* src = (t < 7) ? bq : (t < 14) ? bk : bv;
        b4[t] = ((const float4*)src)[t % 7];
    }
    __syncthreads();

    const int r = row0 + tid;
    const int b = r >> 10, s = r & 1023;

    float x[NIN];
    #pragma unroll
    for (int i = 0; i < NIN; ++i) x[i] = xs[tid * NIN + i];

    float4 q[NH], k[NH], v[NH];
    #pragma unroll
    for (int j4 = 0; j4 < NH; ++j4) { q[j4] = b4[j4]; k[j4] = b4[7 + j4]; v[j4] = b4[14 + j4]; }

    #pragma unroll
    for (int i = 0; i < NIN; ++i) {
        const float xi = x[i];
        #pragma unroll
        for (int j4 = 0; j4 < NH; ++j4) {
            float4 wq = w4[i * 7 + j4];
            float4 wk = w4[49 + i * 7 + j4];
            float4 wv = w4[98 + i * 7 + j4];
            q[j4].x += xi * wq.x; q[j4].y += xi * wq.y; q[j4].z += xi * wq.z; q[j4].w += xi * wq.w;
            k[j4].x += xi * wk.x; k[j4].y += xi * wk.y; k[j4].z += xi * wk.z; k[j4].w += xi * wk.w;
            v[j4].x += xi * wv.x; v[j4].y += xi * wv.y; v[j4].z += xi * wv.z; v[j4].w += xi * wv.w;
        }
    }

    const float qs_scale = 0.5f * 1.4426950408889634f;  // (1/sqrt(4)) * log2(e)
    #pragma unroll
    for (int j4 = 0; j4 < NH; ++j4) {
        const int idx = (b * NH + j4) * SS + s;   // float4 index
        float4 qs = make_float4(qs_scale * q[j4].x, qs_scale * q[j4].y,
                                qs_scale * q[j4].z, qs_scale * q[j4].w);
        ((float4*)Qo)[idx] = qs;
        ((float4*)Ko)[idx] = k[j4];
        ((float4*)Vo)[idx] = v[j4];
    }
}

// ---------------------------------------------------------------------------
// Kernel 2: attention 1. Block = (b,h,qtile 128), 512 threads (8 waves),
// 896 blocks. Thread (ql=tid&63, kq=tid>>6) owns TWO queries {qt*128 + ql,
// +64} over the 128-key slice [kq*128, kq*128+128).
//
// R(this): K/V are read DIRECTLY from global via wave-uniform addresses.
// kq is forced uniform with readfirstlane so the compiler's divergence
// analysis can prove Kg[kk]/Vg[kk] uniform -> s_load_dwordx4 into SGPRs
// (SMEM pipe). Rationale: the previous LDS-broadcast ds_read_b128 pair
// cost ~1 KB of VGPR-writeback per instruction (broadcast still pays full
// 64-lane return bandwidth, ~12cy each, m134) which was the marginal
// resource -- VALUBusy 61% with zero bank conflicts. SGPR operands feed
// the FMAs directly (1 SGPR/instr, legal). LDS staging phase + its
// barrier deleted; LDS now only holds the 20 KB merge buffers.
// Total K/V bytes from L2 unchanged (each wave loads only its 4 KB slice).
// ---------------------------------------------------------------------------
__global__ __launch_bounds__(512) void k_attn1(
    const float* __restrict__ Qo, const float* __restrict__ Ko,
    const float* __restrict__ Vo, float* __restrict__ A)
{
    __shared__ float4 pacc[8 * 128];   // 16 KB merge buffer
    __shared__ float  pl[8 * 128];     //  4 KB merge buffer

    const int bh  = blockIdx.x >> 3;
    const int qt  = blockIdx.x & 7;
    const int tid = threadIdx.x;

    const int ql = tid & 63;
    const int kq = __builtin_amdgcn_readfirstlane(tid >> 6);  // wave id, FORCED uniform

    const float4* __restrict__ Kg = (const float4*)Ko + (size_t)bh * SS;
    const float4* __restrict__ Vg = (const float4*)Vo + (size_t)bh * SS;

    float4 qv[2];
    #pragma unroll
    for (int r = 0; r < 2; ++r)
        qv[r] = ((const float4*)Qo)[(size_t)bh * SS + qt * 128 + r * 64 + ql];

    float4 acc[2];
    float  l[2];
    #pragma unroll
    for (int r = 0; r < 2; ++r) { acc[r] = make_float4(0.f, 0.f, 0.f, 0.f); l[r] = 0.f; }

    const int k0 = kq << 7;
    #pragma unroll 8
    for (int kk = k0; kk < k0 + 128; ++kk) {
        float4 kr = Kg[kk];           // wave-uniform -> s_load (SGPR), no LDS
        float4 vr = Vg[kk];
        #pragma unroll
        for (int r = 0; r < 2; ++r) {
            float s = qv[r].x * kr.x + qv[r].y * kr.y + qv[r].z * kr.z + qv[r].w * kr.w;
            float p = EXP2F(s);
            l[r] += p;
            acc[r].x += p * vr.x; acc[r].y += p * vr.y;
            acc[r].z += p * vr.z; acc[r].w += p * vr.w;
        }
    }

    #pragma unroll
    for (int r = 0; r < 2; ++r) {
        pacc[kq * 128 + r * 64 + ql] = acc[r];
        pl[kq * 128 + r * 64 + ql]   = l[r];
    }
    __syncthreads();

    // merge the 8 k-slices: threads 0..127 own query qt*128 + tid
    if (tid < 128) {
        float4 a  = pacc[tid];
        float  ll = pl[tid];
        #pragma unroll
        for (int j = 1; j < 8; ++j) {
            float4 t = pacc[j * 128 + tid];
            a.x += t.x; a.y += t.y; a.z += t.z; a.w += t.w;
            ll += pl[j * 128 + tid];
        }
        const float inv = 1.f / ll;
        const int b = bh / NH, h = bh % NH;
        const int q = qt * 128 + tid;
        ((float4*)A)[(size_t)(b * SS + q) * NH + h] =
            make_float4(a.x * inv, a.y * inv, a.z * inv, a.w * inv);
    }
}

// ---------------------------------------------------------------------------
// Kernel 3: LayerNorm(28) + FFN(28->7)+ReLU+residual -> out (output 0),
// then Q2 (row-major, pre-scaled by (1/sqrt(7))*log2e for exp2 softmax)
// and K2 TRANSPOSED: K2T[b][d][s].
// ---------------------------------------------------------------------------
__global__ __launch_bounds__(256) void k_lnffn(
    const float* __restrict__ A, const float* __restrict__ inp,
    const float* __restrict__ lnw, const float* __restrict__ lnb,
    const float* __restrict__ W1, const float* __restrict__ b1,
    const float* __restrict__ Wq2, const float* __restrict__ bq2,
    const float* __restrict__ Wk2, const float* __restrict__ bk2,
    float* __restrict__ outp, float* __restrict__ Q2, float* __restrict__ K2T)
{
    const int r = blockIdx.x * 256 + threadIdx.x;

    float y[NHID];
    const float4* Ar = (const float4*)A + (size_t)r * 7;
    float mu = 0.f;
    #pragma unroll
    for (int j4 = 0; j4 < 7; ++j4) {
        float4 t = Ar[j4];
        y[4 * j4 + 0] = t.x; y[4 * j4 + 1] = t.y; y[4 * j4 + 2] = t.z; y[4 * j4 + 3] = t.w;
        mu += t.x + t.y + t.z + t.w;
    }
    mu *= (1.f / NHID);
    float var = 0.f;
    #pragma unroll
    for (int j = 0; j < NHID; ++j) { float d = y[j] - mu; var += d * d; }
    var *= (1.f / NHID);
    const float rstd = rsqrtf(var + 1e-5f);
    #pragma unroll
    for (int j = 0; j < NHID; ++j) y[j] = (y[j] - mu) * rstd * lnw[j] + lnb[j];

    float o[NIN];
    #pragma unroll
    for (int i = 0; i < NIN; ++i) {
        float a = b1[i];
        #pragma unroll
        for (int j = 0; j < NHID; ++j) a += y[j] * W1[j * NIN + i];
        o[i] = fmaxf(a, 0.f) + inp[r * NIN + i];
        outp[r * NIN + i] = o[i];
    }

    const float rs7l2e = 0.3779644730092272f * 1.4426950408889634f;  // (1/sqrt7)*log2e
    const int b = r >> 10, s = r & 1023;
    float* K2Tb = K2T + ((size_t)b * NHID) * SS + s;
    float4* Q2r = (float4*)Q2 + (size_t)r * 7;
    #pragma unroll
    for (int j4 = 0; j4 < 7; ++j4) {
        float qq[4];
        #pragma unroll
        for (int c = 0; c < 4; ++c) {
            int j = 4 * j4 + c;
            float aq = bq2[j], ak = bk2[j];
            #pragma unroll
            for (int i = 0; i < NIN; ++i) {
                aq += o[i] * Wq2[i * NHID + j];
                ak += o[i] * Wk2[i * NHID + j];
            }
            qq[c] = aq * rs7l2e;
            K2Tb[(size_t)j * SS] = ak;      // coalesced per-j
        }
        Q2r[j4] = make_float4(qq[0], qq[1], qq[2], qq[3]);
    }
}

// ---------------------------------------------------------------------------
// Kernel 4: attention 2 weights. Wave-autonomous, 4 rows/wave; dynamic
// 28-dim loop (q via LDS scalar broadcast) + __launch_bounds__(256,4)
// keeps VGPR at the 128 cap without spill (R6: total dropped 216->187).
// exp2 softmax (Q2 pre-scaled by log2e in k_lnffn).
// ---------------------------------------------------------------------------
#define QR 4
__global__ __launch_bounds__(256, 4) void k_attn2(
    const float* __restrict__ Q2, const float* __restrict__ K2T,
    float* __restrict__ out2)
{
    __shared__ float q2s[16 * NHID];   // 1792 B

    const int tid  = threadIdx.x;
    const int lane = tid & 63;
    const int wid  = tid >> 6;
    const int row0 = blockIdx.x * 16;          // global row = b*1024 + s
    const int b    = row0 >> 10;

    if (tid < 112) ((float4*)q2s)[tid] = ((const float4*)Q2)[(size_t)row0 * 7 + tid];
    __syncthreads();

    const float*  qw  = q2s + wid * QR * NHID;              // this wave's 4 rows
    const float4* K2b = (const float4*)(K2T + (size_t)b * NHID * SS);  // [28][256] f4

    float4 p0[QR], p1[QR], p2[QR], p3[QR];     // p[r][j]: 64 VGPRs
    #pragma unroll
    for (int r = 0; r < QR; ++r) {
        p0[r] = make_float4(0.f, 0.f, 0.f, 0.f);
        p1[r] = make_float4(0.f, 0.f, 0.f, 0.f);
        p2[r] = make_float4(0.f, 0.f, 0.f, 0.f);
        p3[r] = make_float4(0.f, 0.f, 0.f, 0.f);
    }

    #pragma unroll 2
    for (int d = 0; d < NHID; ++d) {
        float4 kt0 = K2b[d * 256 +       lane];
        float4 kt1 = K2b[d * 256 +  64 + lane];
        float4 kt2 = K2b[d * 256 + 128 + lane];
        float4 kt3 = K2b[d * 256 + 192 + lane];
        #pragma unroll
        for (int r = 0; r < QR; ++r) {
            const float qd = qw[r * NHID + d];  // LDS scalar broadcast
            p0[r].x += qd * kt0.x; p0[r].y += qd * kt0.y;
            p0[r].z += qd * kt0.z; p0[r].w += qd * kt0.w;
            p1[r].x += qd * kt1.x; p1[r].y += qd * kt1.y;
            p1[r].z += qd * kt1.z; p1[r].w += qd * kt1.w;
            p2[r].x += qd * kt2.x; p2[r].y += qd * kt2.y;
            p2[r].z += qd * kt2.z; p2[r].w += qd * kt2.w;
            p3[r].x += qd * kt3.x; p3[r].y += qd * kt3.y;
            p3[r].z += qd * kt3.z; p3[r].w += qd * kt3.w;
        }
    }

    #pragma unroll
    for (int r = 0; r < QR; ++r) {
        p0[r].x = EXP2F(p0[r].x); p0[r].y = EXP2F(p0[r].y);
        p0[r].z = EXP2F(p0[r].z); p0[r].w = EXP2F(p0[r].w);
        p1[r].x = EXP2F(p1[r].x); p1[r].y = EXP2F(p1[r].y);
        p1[r].z = EXP2F(p1[r].z); p1[r].w = EXP2F(p1[r].w);
        p2[r].x = EXP2F(p2[r].x); p2[r].y = EXP2F(p2[r].y);
        p2[r].z = EXP2F(p2[r].z); p2[r].w = EXP2F(p2[r].w);
        p3[r].x = EXP2F(p3[r].x); p3[r].y = EXP2F(p3[r].y);
        p3[r].z = EXP2F(p3[r].z); p3[r].w = EXP2F(p3[r].w);
        float sum = p0[r].x + p0[r].y + p0[r].z + p0[r].w
                  + p1[r].x + p1[r].y + p1[r].z + p1[r].w
                  + p2[r].x + p2[r].y + p2[r].z + p2[r].w
                  + p3[r].x + p3[r].y + p3[r].z + p3[r].w;
        #pragma unroll
        for (int off = 1; off < 64; off <<= 1) sum += __shfl_xor(sum, off);
        const float iv = 1.f / sum;
        float4* orow = (float4*)(out2 + ((size_t)row0 + wid * QR + r) * SS);
        orow[       lane] = make_float4(p0[r].x * iv, p0[r].y * iv, p0[r].z * iv, p0[r].w * iv);
        orow[ 64 + lane] = make_float4(p1[r].x * iv, p1[r].y * iv, p1[r].z * iv, p1[r].w * iv);
        orow[128 + lane] = make_float4(p2[r].x * iv, p2[r].y * iv, p2[r].z * iv, p2[r].w * iv);
        orow[192 + lane] = make_float4(p3[r].x * iv, p3[r].y * iv, p3[r].z * iv, p3[r].w * iv);
    }
}

// ---------------------------------------------------------------------------
extern "C" void kernel_launch(void* const* d_in, const int* in_sizes, int n_in,
                              void* d_out, int out_size, void* d_ws, size_t ws_size,
                              hipStream_t stream) {
    const float* inp = (const float*)d_in[0];
    const float* Wq  = (const float*)d_in[1];
    const float* bq  = (const float*)d_in[2];
    const float* Wk  = (const float*)d_in[3];
    const float* bk  = (const float*)d_in[4];
    const float* Wv  = (const float*)d_in[5];
    const float* bv  = (const float*)d_in[6];
    const float* lnw = (const float*)d_in[7];
    const float* lnb = (const float*)d_in[8];
    const float* W1  = (const float*)d_in[9];
    const float* b1  = (const float*)d_in[10];
    const float* Wq2 = (const float*)d_in[11];
    const float* bq2 = (const float*)d_in[12];
    const float* Wk2 = (const float*)d_in[13];
    const float* bk2 = (const float*)d_in[14];

    float* out0 = (float*)d_out;                 // [16,1024,7]
    float* out2 = out0 + ROWS * NIN;             // [16,1024,1024]

    float* ws = (float*)d_ws;
    float* Qo  = ws;
    float* Ko  = ws + (size_t)QKV_ELEMS;
    float* Vo  = ws + (size_t)2 * QKV_ELEMS;
    float* A   = ws + (size_t)3 * QKV_ELEMS;
    float* Q2  = ws + (size_t)4 * QKV_ELEMS;
    float* K2T = ws + (size_t)5 * QKV_ELEMS;     // [B,28,S]

    k_proj <<<ROWS / 256, 256, 0, stream>>>(inp, Wq, bq, Wk, bk, Wv, bv, Qo, Ko, Vo);
    k_attn1<<<BB * NH * 8, 512, 0, stream>>>(Qo, Ko, Vo, A);
    k_lnffn<<<ROWS / 256, 256, 0, stream>>>(A, inp, lnw, lnb, W1, b1,
                                            Wq2, bq2, Wk2, bk2, out0, Q2, K2T);
    k_attn2<<<ROWS / 16, 256, 0, stream>>>(Q2, K2T, out2);
}

// Round 2
// 183.228 us; speedup vs baseline: 1.3384x; 1.3384x over previous
//
#include <hip/hip_runtime.h>

// Problem constants (fixed by reference)
#define BB 16
#define SS 1024
#define NIN 7
#define NHID 28
#define NH 7
#define DH 4

// Raw 2^x (v_exp_f32). NOTE: __exp2f does NOT exist in HIP device code
// (R7 compile failure -- glibc math.h macro collision). exp(x) == exp2(x*log2e);
// the log2e factor is folded into the Q / Q2 projection scales.
#define EXP2F(x) __builtin_amdgcn_exp2f(x)

constexpr int ROWS = BB * SS;                 // 16384
constexpr int QKV_ELEMS = BB * NH * SS * DH;  // 458752 floats per tensor

// ---------------------------------------------------------------------------
// Kernel 1: QKV projection. inputs [B,S,7] @ W[7,28] + b -> Q,K,V in
// head-major layout [B][H][S][4]. Q pre-scaled by (1/sqrt(DH)) * log2(e)
// so attention-1 can use exp2 instead of exp (saves one v_mul per pair).
// ---------------------------------------------------------------------------
__global__ __launch_bounds__(256) void k_proj(
    const float* __restrict__ inp,
    const float* __restrict__ Wq, const float* __restrict__ bq,
    const float* __restrict__ Wk, const float* __restrict__ bk,
    const float* __restrict__ Wv, const float* __restrict__ bv,
    float* __restrict__ Qo, float* __restrict__ Ko, float* __restrict__ Vo)
{
    __shared__ float  xs[256 * NIN];   // 7 KB: 256 rows of inputs
    __shared__ float4 w4[147];         // Wq(49) | Wk(49) | Wv(49) as float4
    __shared__ float4 b4[21];          // bq(7) | bk(7) | bv(7)

    const int tid  = threadIdx.x;
    const int row0 = blockIdx.x * 256;

    #pragma unroll
    for (int i = 0; i < NIN; ++i) xs[tid + 256 * i] = inp[row0 * NIN + tid + 256 * i];

    if (tid < 147) {
        const float* src = (tid < 49) ? Wq : (tid < 98) ? Wk : Wv;
        int off = (tid < 49) ? tid : (tid < 98) ? tid - 49 : tid - 98;
        w4[tid] = ((const float4*)src)[off];
    } else if (tid < 168) {
        int t = tid - 147;
        const float* src = (t < 7) ? bq : (t < 14) ? bk : bv;
        b4[t] = ((const float4*)src)[t % 7];
    }
    __syncthreads();

    const int r = row0 + tid;
    const int b = r >> 10, s = r & 1023;

    float x[NIN];
    #pragma unroll
    for (int i = 0; i < NIN; ++i) x[i] = xs[tid * NIN + i];

    float4 q[NH], k[NH], v[NH];
    #pragma unroll
    for (int j4 = 0; j4 < NH; ++j4) { q[j4] = b4[j4]; k[j4] = b4[7 + j4]; v[j4] = b4[14 + j4]; }

    #pragma unroll
    for (int i = 0; i < NIN; ++i) {
        const float xi = x[i];
        #pragma unroll
        for (int j4 = 0; j4 < NH; ++j4) {
            float4 wq = w4[i * 7 + j4];
            float4 wk = w4[49 + i * 7 + j4];
            float4 wv = w4[98 + i * 7 + j4];
            q[j4].x += xi * wq.x; q[j4].y += xi * wq.y; q[j4].z += xi * wq.z; q[j4].w += xi * wq.w;
            k[j4].x += xi * wk.x; k[j4].y += xi * wk.y; k[j4].z += xi * wk.z; k[j4].w += xi * wk.w;
            v[j4].x += xi * wv.x; v[j4].y += xi * wv.y; v[j4].z += xi * wv.z; v[j4].w += xi * wv.w;
        }
    }

    const float qs_scale = 0.5f * 1.4426950408889634f;  // (1/sqrt(4)) * log2(e)
    #pragma unroll
    for (int j4 = 0; j4 < NH; ++j4) {
        const int idx = (b * NH + j4) * SS + s;   // float4 index
        float4 qs = make_float4(qs_scale * q[j4].x, qs_scale * q[j4].y,
                                qs_scale * q[j4].z, qs_scale * q[j4].w);
        ((float4*)Qo)[idx] = qs;
        ((float4*)Ko)[idx] = k[j4];
        ((float4*)Vo)[idx] = v[j4];
    }
}

// ---------------------------------------------------------------------------
// Kernel 2: attention 1. R1 post-mortem: s_load scalarization of K/V
// serialized on SMEM latency (VALUBusy 61->27%, dur 50->107us) -- REVERTED
// to LDS staging + wave-uniform broadcast ds_read (single-address, 0 bank
// conflicts).
//
// R2: amortize the broadcast. The LDS pipe cost is 2 ds_read_b128 per
// key-iteration per wave (~1 KB VGPR writeback each, ~24us chip-wide at
// R0's 2 queries/thread -- the reason VALUBusy plateaued at 61%). Now each
// thread owns FOUR queries {qt*256 + r*64 + ql, r=0..3}, so one K/V
// broadcast pair serves 256 pairs instead of 128: ds instruction count
// halves (1.84M -> 0.92M). Key summation order is IDENTICAL to R0
// (8 slices x 128 keys, merged j=0..7) -> bit-identical output.
// Block = 256q x 1024k tile, 512 thr, grid 112 bh x 4 qt = 448.
// LDS: 32KB K/V staging, overlaid by 40KB merge (8 x 256 x 20B).
// ---------------------------------------------------------------------------
__global__ __launch_bounds__(512) void k_attn1(
    const float* __restrict__ Qo, const float* __restrict__ Ko,
    const float* __restrict__ Vo, float* __restrict__ A)
{
    __shared__ char smem[40960];
    float4* Ksh  = (float4*)smem;             // [1024] 16 KB (phase 1)
    float4* Vsh  = (float4*)(smem + 16384);   // [1024] 16 KB (phase 1)
    float4* pacc = (float4*)smem;             // [8][256] 32 KB (phase 2 overlay)
    float*  pl   = (float*)(smem + 32768);    // [8][256]  8 KB (phase 2 overlay)

    const int bh  = blockIdx.x >> 2;
    const int qt  = blockIdx.x & 3;
    const int tid = threadIdx.x;

    const float4* Kg = (const float4*)Ko + (size_t)bh * SS;
    const float4* Vg = (const float4*)Vo + (size_t)bh * SS;
    #pragma unroll
    for (int i = 0; i < 2; ++i) {
        Ksh[tid + 512 * i] = Kg[tid + 512 * i];
        Vsh[tid + 512 * i] = Vg[tid + 512 * i];
    }
    __syncthreads();

    const int ql = tid & 63;
    const int kq = tid >> 6;          // wave id; uniform within wave

    float4 qv[4];
    #pragma unroll
    for (int r = 0; r < 4; ++r)
        qv[r] = ((const float4*)Qo)[(size_t)bh * SS + qt * 256 + r * 64 + ql];

    float4 acc[4];
    float  l[4];
    #pragma unroll
    for (int r = 0; r < 4; ++r) { acc[r] = make_float4(0.f, 0.f, 0.f, 0.f); l[r] = 0.f; }

    const int k0 = kq << 7;
    #pragma unroll 4
    for (int kk = k0; kk < k0 + 128; ++kk) {
        float4 kr = Ksh[kk];          // single broadcast addr per wave
        float4 vr = Vsh[kk];
        #pragma unroll
        for (int r = 0; r < 4; ++r) {
            float s = qv[r].x * kr.x + qv[r].y * kr.y + qv[r].z * kr.z + qv[r].w * kr.w;
            float p = EXP2F(s);
            l[r] += p;
            acc[r].x += p * vr.x; acc[r].y += p * vr.y;
            acc[r].z += p * vr.z; acc[r].w += p * vr.w;
        }
    }

    __syncthreads();   // all K/V reads done; smem reused as merge buffers
    #pragma unroll
    for (int r = 0; r < 4; ++r) {
        pacc[kq * 256 + r * 64 + ql] = acc[r];
        pl[kq * 256 + r * 64 + ql]   = l[r];
    }
    __syncthreads();

    // merge the 8 k-slices: threads 0..255 own query qt*256 + tid
    if (tid < 256) {
        float4 a  = pacc[tid];
        float  ll = pl[tid];
        #pragma unroll
        for (int j = 1; j < 8; ++j) {
            float4 t = pacc[j * 256 + tid];
            a.x += t.x; a.y += t.y; a.z += t.z; a.w += t.w;
            ll += pl[j * 256 + tid];
        }
        const float inv = 1.f / ll;
        const int b = bh / NH, h = bh % NH;
        const int q = qt * 256 + tid;
        ((float4*)A)[(size_t)(b * SS + q) * NH + h] =
            make_float4(a.x * inv, a.y * inv, a.z * inv, a.w * inv);
    }
}

// ---------------------------------------------------------------------------
// Kernel 3: LayerNorm(28) + FFN(28->7)+ReLU+residual -> out (output 0),
// then Q2 (row-major, pre-scaled by (1/sqrt(7))*log2e for exp2 softmax)
// and K2 TRANSPOSED: K2T[b][d][s].
// ---------------------------------------------------------------------------
__global__ __launch_bounds__(256) void k_lnffn(
    const float* __restrict__ A, const float* __restrict__ inp,
    const float* __restrict__ lnw, const float* __restrict__ lnb,
    const float* __restrict__ W1, const float* __restrict__ b1,
    const float* __restrict__ Wq2, const float* __restrict__ bq2,
    const float* __restrict__ Wk2, const float* __restrict__ bk2,
    float* __restrict__ outp, float* __restrict__ Q2, float* __restrict__ K2T)
{
    const int r = blockIdx.x * 256 + threadIdx.x;

    float y[NHID];
    const float4* Ar = (const float4*)A + (size_t)r * 7;
    float mu = 0.f;
    #pragma unroll
    for (int j4 = 0; j4 < 7; ++j4) {
        float4 t = Ar[j4];
        y[4 * j4 + 0] = t.x; y[4 * j4 + 1] = t.y; y[4 * j4 + 2] = t.z; y[4 * j4 + 3] = t.w;
        mu += t.x + t.y + t.z + t.w;
    }
    mu *= (1.f / NHID);
    float var = 0.f;
    #pragma unroll
    for (int j = 0; j < NHID; ++j) { float d = y[j] - mu; var += d * d; }
    var *= (1.f / NHID);
    const float rstd = rsqrtf(var + 1e-5f);
    #pragma unroll
    for (int j = 0; j < NHID; ++j) y[j] = (y[j] - mu) * rstd * lnw[j] + lnb[j];

    float o[NIN];
    #pragma unroll
    for (int i = 0; i < NIN; ++i) {
        float a = b1[i];
        #pragma unroll
        for (int j = 0; j < NHID; ++j) a += y[j] * W1[j * NIN + i];
        o[i] = fmaxf(a, 0.f) + inp[r * NIN + i];
        outp[r * NIN + i] = o[i];
    }

    const float rs7l2e = 0.3779644730092272f * 1.4426950408889634f;  // (1/sqrt7)*log2e
    const int b = r >> 10, s = r & 1023;
    float* K2Tb = K2T + ((size_t)b * NHID) * SS + s;
    float4* Q2r = (float4*)Q2 + (size_t)r * 7;
    #pragma unroll
    for (int j4 = 0; j4 < 7; ++j4) {
        float qq[4];
        #pragma unroll
        for (int c = 0; c < 4; ++c) {
            int j = 4 * j4 + c;
            float aq = bq2[j], ak = bk2[j];
            #pragma unroll
            for (int i = 0; i < NIN; ++i) {
                aq += o[i] * Wq2[i * NHID + j];
                ak += o[i] * Wk2[i * NHID + j];
            }
            qq[c] = aq * rs7l2e;
            K2Tb[(size_t)j * SS] = ak;      // coalesced per-j
        }
        Q2r[j4] = make_float4(qq[0], qq[1], qq[2], qq[3]);
    }
}

// ---------------------------------------------------------------------------
// Kernel 4: attention 2 weights. Wave-autonomous, 4 rows/wave; dynamic
// 28-dim loop (q via LDS scalar broadcast) + __launch_bounds__(256,4)
// keeps VGPR at the 128 cap without spill (R6: total dropped 216->187).
// exp2 softmax (Q2 pre-scaled by log2e in k_lnffn).
// ---------------------------------------------------------------------------
#define QR 4
__global__ __launch_bounds__(256, 4) void k_attn2(
    const float* __restrict__ Q2, const float* __restrict__ K2T,
    float* __restrict__ out2)
{
    __shared__ float q2s[16 * NHID];   // 1792 B

    const int tid  = threadIdx.x;
    const int lane = tid & 63;
    const int wid  = tid >> 6;
    const int row0 = blockIdx.x * 16;          // global row = b*1024 + s
    const int b    = row0 >> 10;

    if (tid < 112) ((float4*)q2s)[tid] = ((const float4*)Q2)[(size_t)row0 * 7 + tid];
    __syncthreads();

    const float*  qw  = q2s + wid * QR * NHID;              // this wave's 4 rows
    const float4* K2b = (const float4*)(K2T + (size_t)b * NHID * SS);  // [28][256] f4

    float4 p0[QR], p1[QR], p2[QR], p3[QR];     // p[r][j]: 64 VGPRs
    #pragma unroll
    for (int r = 0; r < QR; ++r) {
        p0[r] = make_float4(0.f, 0.f, 0.f, 0.f);
        p1[r] = make_float4(0.f, 0.f, 0.f, 0.f);
        p2[r] = make_float4(0.f, 0.f, 0.f, 0.f);
        p3[r] = make_float4(0.f, 0.f, 0.f, 0.f);
    }

    #pragma unroll 2
    for (int d = 0; d < NHID; ++d) {
        float4 kt0 = K2b[d * 256 +       lane];
        float4 kt1 = K2b[d * 256 +  64 + lane];
        float4 kt2 = K2b[d * 256 + 128 + lane];
        float4 kt3 = K2b[d * 256 + 192 + lane];
        #pragma unroll
        for (int r = 0; r < QR; ++r) {
            const float qd = qw[r * NHID + d];  // LDS scalar broadcast
            p0[r].x += qd * kt0.x; p0[r].y += qd * kt0.y;
            p0[r].z += qd * kt0.z; p0[r].w += qd * kt0.w;
            p1[r].x += qd * kt1.x; p1[r].y += qd * kt1.y;
            p1[r].z += qd * kt1.z; p1[r].w += qd * kt1.w;
            p2[r].x += qd * kt2.x; p2[r].y += qd * kt2.y;
            p2[r].z += qd * kt2.z; p2[r].w += qd * kt2.w;
            p3[r].x += qd * kt3.x; p3[r].y += qd * kt3.y;
            p3[r].z += qd * kt3.z; p3[r].w += qd * kt3.w;
        }
    }

    #pragma unroll
    for (int r = 0; r < QR; ++r) {
        p0[r].x = EXP2F(p0[r].x); p0[r].y = EXP2F(p0[r].y);
        p0[r].z = EXP2F(p0[r].z); p0[r].w = EXP2F(p0[r].w);
        p1[r].x = EXP2F(p1[r].x); p1[r].y = EXP2F(p1[r].y);
        p1[r].z = EXP2F(p1[r].z); p1[r].w = EXP2F(p1[r].w);
        p2[r].x = EXP2F(p2[r].x); p2[r].y = EXP2F(p2[r].y);
        p2[r].z = EXP2F(p2[r].z); p2[r].w = EXP2F(p2[r].w);
        p3[r].x = EXP2F(p3[r].x); p3[r].y = EXP2F(p3[r].y);
        p3[r].z = EXP2F(p3[r].z); p3[r].w = EXP2F(p3[r].w);
        float sum = p0[r].x + p0[r].y + p0[r].z + p0[r].w
                  + p1[r].x + p1[r].y + p1[r].z + p1[r].w
                  + p2[r].x + p2[r].y + p2[r].z + p2[r].w
                  + p3[r].x + p3[r].y + p3[r].z + p3[r].w;
        #pragma unroll
        for (int off = 1; off < 64; off <<= 1) sum += __shfl_xor(sum, off);
        const float iv = 1.f / sum;
        float4* orow = (float4*)(out2 + ((size_t)row0 + wid * QR + r) * SS);
        orow[       lane] = make_float4(p0[r].x * iv, p0[r].y * iv, p0[r].z * iv, p0[r].w * iv);
        orow[ 64 + lane] = make_float4(p1[r].x * iv, p1[r].y * iv, p1[r].z * iv, p1[r].w * iv);
        orow[128 + lane] = make_float4(p2[r].x * iv, p2[r].y * iv, p2[r].z * iv, p2[r].w * iv);
        orow[192 + lane] = make_float4(p3[r].x * iv, p3[r].y * iv, p3[r].z * iv, p3[r].w * iv);
    }
}

// ---------------------------------------------------------------------------
extern "C" void kernel_launch(void* const* d_in, const int* in_sizes, int n_in,
                              void* d_out, int out_size, void* d_ws, size_t ws_size,
                              hipStream_t stream) {
    const float* inp = (const float*)d_in[0];
    const float* Wq  = (const float*)d_in[1];
    const float* bq  = (const float*)d_in[2];
    const float* Wk  = (const float*)d_in[3];
    const float* bk  = (const float*)d_in[4];
    const float* Wv  = (const float*)d_in[5];
    const float* bv  = (const float*)d_in[6];
    const float* lnw = (const float*)d_in[7];
    const float* lnb = (const float*)d_in[8];
    const float* W1  = (const float*)d_in[9];
    const float* b1  = (const float*)d_in[10];
    const float* Wq2 = (const float*)d_in[11];
    const float* bq2 = (const float*)d_in[12];
    const float* Wk2 = (const float*)d_in[13];
    const float* bk2 = (const float*)d_in[14];

    float* out0 = (float*)d_out;                 // [16,1024,7]
    float* out2 = out0 + ROWS * NIN;             // [16,1024,1024]

    float* ws = (float*)d_ws;
    float* Qo  = ws;
    float* Ko  = ws + (size_t)QKV_ELEMS;
    float* Vo  = ws + (size_t)2 * QKV_ELEMS;
    float* A   = ws + (size_t)3 * QKV_ELEMS;
    float* Q2  = ws + (size_t)4 * QKV_ELEMS;
    float* K2T = ws + (size_t)5 * QKV_ELEMS;     // [B,28,S]

    k_proj <<<ROWS / 256, 256, 0, stream>>>(inp, Wq, bq, Wk, bk, Wv, bv, Qo, Ko, Vo);
    k_attn1<<<BB * NH * 4, 512, 0, stream>>>(Qo, Ko, Vo, A);
    k_lnffn<<<ROWS / 256, 256, 0, stream>>>(A, inp, lnw, lnb, W1, b1,
                                            Wq2, bq2, Wk2, bk2, out0, Q2, K2T);
    k_attn2<<<ROWS / 16, 256, 0, stream>>>(Q2, K2T, out2);
}

// Round 3
// 175.591 us; speedup vs baseline: 1.3966x; 1.0435x over previous
//
#include <hip/hip_runtime.h>

// Problem constants (fixed by reference)
#define BB 16
#define SS 1024
#define NIN 7
#define NHID 28
#define NH 7
#define DH 4

// Raw 2^x (v_exp_f32). NOTE: __exp2f does NOT exist in HIP device code
// (R7 compile failure -- glibc math.h macro collision). exp(x) == exp2(x*log2e);
// the log2e factor is folded into the Q / Q2 projection scales.
#define EXP2F(x) __builtin_amdgcn_exp2f(x)

constexpr int ROWS = BB * SS;                 // 16384
constexpr int QKV_ELEMS = BB * NH * SS * DH;  // 458752 floats per tensor
constexpr int CHUNK_STRIDE = BB * NH * SS;    // 114688: per-ks-chunk stride (f4 / f1 units)

// ---------------------------------------------------------------------------
// Kernel 1: QKV projection. inputs [B,S,7] @ W[7,28] + b -> Q,K,V in
// head-major layout [B][H][S][4]. Q pre-scaled by (1/sqrt(DH)) * log2(e)
// so attention-1 can use exp2 instead of exp (saves one v_mul per pair).
// ---------------------------------------------------------------------------
__global__ __launch_bounds__(256) void k_proj(
    const float* __restrict__ inp,
    const float* __restrict__ Wq, const float* __restrict__ bq,
    const float* __restrict__ Wk, const float* __restrict__ bk,
    const float* __restrict__ Wv, const float* __restrict__ bv,
    float* __restrict__ Qo, float* __restrict__ Ko, float* __restrict__ Vo)
{
    __shared__ float  xs[256 * NIN];   // 7 KB: 256 rows of inputs
    __shared__ float4 w4[147];         // Wq(49) | Wk(49) | Wv(49) as float4
    __shared__ float4 b4[21];          // bq(7) | bk(7) | bv(7)

    const int tid  = threadIdx.x;
    const int row0 = blockIdx.x * 256;

    #pragma unroll
    for (int i = 0; i < NIN; ++i) xs[tid + 256 * i] = inp[row0 * NIN + tid + 256 * i];

    if (tid < 147) {
        const float* src = (tid < 49) ? Wq : (tid < 98) ? Wk : Wv;
        int off = (tid < 49) ? tid : (tid < 98) ? tid - 49 : tid - 98;
        w4[tid] = ((const float4*)src)[off];
    } else if (tid < 168) {
        int t = tid - 147;
        const float* src = (t < 7) ? bq : (t < 14) ? bk : bv;
        b4[t] = ((const float4*)src)[t % 7];
    }
    __syncthreads();

    const int r = row0 + tid;
    const int b = r >> 10, s = r & 1023;

    float x[NIN];
    #pragma unroll
    for (int i = 0; i < NIN; ++i) x[i] = xs[tid * NIN + i];

    float4 q[NH], k[NH], v[NH];
    #pragma unroll
    for (int j4 = 0; j4 < NH; ++j4) { q[j4] = b4[j4]; k[j4] = b4[7 + j4]; v[j4] = b4[14 + j4]; }

    #pragma unroll
    for (int i = 0; i < NIN; ++i) {
        const float xi = x[i];
        #pragma unroll
        for (int j4 = 0; j4 < NH; ++j4) {
            float4 wq = w4[i * 7 + j4];
            float4 wk = w4[49 + i * 7 + j4];
            float4 wv = w4[98 + i * 7 + j4];
            q[j4].x += xi * wq.x; q[j4].y += xi * wq.y; q[j4].z += xi * wq.z; q[j4].w += xi * wq.w;
            k[j4].x += xi * wk.x; k[j4].y += xi * wk.y; k[j4].z += xi * wk.z; k[j4].w += xi * wk.w;
            v[j4].x += xi * wv.x; v[j4].y += xi * wv.y; v[j4].z += xi * wv.z; v[j4].w += xi * wv.w;
        }
    }

    const float qs_scale = 0.5f * 1.4426950408889634f;  // (1/sqrt(4)) * log2(e)
    #pragma unroll
    for (int j4 = 0; j4 < NH; ++j4) {
        const int idx = (b * NH + j4) * SS + s;   // float4 index
        float4 qs = make_float4(qs_scale * q[j4].x, qs_scale * q[j4].y,
                                qs_scale * q[j4].z, qs_scale * q[j4].w);
        ((float4*)Qo)[idx] = qs;
        ((float4*)Ko)[idx] = k[j4];
        ((float4*)Vo)[idx] = v[j4];
    }
}

// ---------------------------------------------------------------------------
// Kernel 2: attention 1.
// R1 post-mortem: s_load scalarization serialized on SMEM latency (REVERTED).
// R2 post-mortem: halving ds_read via 4q/thread moved 50.2->48.5us only;
// VALU busy-TIME constant (~29us) across R0/R2 -> LDS pipe was never
// binding. Remaining gap = grid imbalance (448 heavy blocks / 256 CUs =
// 87.5% best case) + 25% occupancy leaving staging/merge latency exposed.
//
// R3: split-K x4. Grid = 112 bh x 4 qt x 4 ks = 1792 blocks == 7/CU
// (perfect balance). Each block stages a 256-key K/V chunk (8 KB) and
// computes a 256q x 256k tile (8 waves x 32-key slices, 4 q/thread --
// same broadcast amortization as R2). In-block 8-slice merge unchanged;
// per-(q,ks) partials (acc4, l) are written UNNORMALIZED to scratch in
// the out2 region of d_out (k_attn2 overwrites it later -- safe by
// stream order). Normalization + 4-chunk reduce folds into k_lnffn.
// LDS 40KB -> 4 blocks/CU -> 32 waves/CU occupancy cap (100%).
// ---------------------------------------------------------------------------
__global__ __launch_bounds__(512) void k_attn1(
    const float* __restrict__ Qo, const float* __restrict__ Ko,
    const float* __restrict__ Vo, float4* __restrict__ Apart,
    float* __restrict__ Lpart)
{
    __shared__ char smem[40960];
    float4* Ksh  = (float4*)smem;             // [256]  4 KB (phase 1)
    float4* Vsh  = (float4*)(smem + 4096);    // [256]  4 KB (phase 1)
    float4* pacc = (float4*)smem;             // [8][256] 32 KB (phase 2 overlay)
    float*  pl   = (float*)(smem + 32768);    // [8][256]  8 KB

    const int bh  = blockIdx.x >> 4;          // 0..111
    const int qt  = (blockIdx.x >> 2) & 3;    // q tile (256 queries)
    const int ks  = blockIdx.x & 3;           // key chunk (256 keys)
    const int tid = threadIdx.x;

    // stage this block's 256-key K/V chunk: waves 0-3 load K, 4-7 load V
    const float4* Kg = (const float4*)Ko + (size_t)bh * SS + (ks << 8);
    const float4* Vg = (const float4*)Vo + (size_t)bh * SS + (ks << 8);
    if (tid < 256) Ksh[tid]       = Kg[tid];
    else           Vsh[tid - 256] = Vg[tid - 256];

    const int ql = tid & 63;
    const int kq = tid >> 6;          // wave id; uniform within wave

    float4 qv[4];                     // independent of LDS: overlaps staging
    #pragma unroll
    for (int r = 0; r < 4; ++r)
        qv[r] = ((const float4*)Qo)[(size_t)bh * SS + (qt << 8) + r * 64 + ql];

    __syncthreads();

    float4 acc[4];
    float  l[4];
    #pragma unroll
    for (int r = 0; r < 4; ++r) { acc[r] = make_float4(0.f, 0.f, 0.f, 0.f); l[r] = 0.f; }

    const int k0 = kq << 5;
    #pragma unroll 4
    for (int kk = k0; kk < k0 + 32; ++kk) {
        float4 kr = Ksh[kk];          // single broadcast addr per wave
        float4 vr = Vsh[kk];
        #pragma unroll
        for (int r = 0; r < 4; ++r) {
            float s = qv[r].x * kr.x + qv[r].y * kr.y + qv[r].z * kr.z + qv[r].w * kr.w;
            float p = EXP2F(s);
            l[r] += p;
            acc[r].x += p * vr.x; acc[r].y += p * vr.y;
            acc[r].z += p * vr.z; acc[r].w += p * vr.w;
        }
    }

    __syncthreads();   // all K/V reads done; smem reused as merge buffers
    #pragma unroll
    for (int r = 0; r < 4; ++r) {
        pacc[kq * 256 + r * 64 + ql] = acc[r];
        pl[kq * 256 + r * 64 + ql]   = l[r];
    }
    __syncthreads();

    // merge the 8 k-slices: threads 0..255 own query qt*256 + tid
    if (tid < 256) {
        float4 a  = pacc[tid];
        float  ll = pl[tid];
        #pragma unroll
        for (int j = 1; j < 8; ++j) {
            float4 t = pacc[j * 256 + tid];
            a.x += t.x; a.y += t.y; a.z += t.z; a.w += t.w;
            ll += pl[j * 256 + tid];
        }
        // unnormalized partial for this 256-key chunk; coalesced in q
        const size_t o = ((size_t)(ks * (BB * NH) + bh) << 10) + (qt << 8) + tid;
        Apart[o] = a;
        Lpart[o] = ll;
    }
}

// ---------------------------------------------------------------------------
// Kernel 3: reduce the 4 split-K partials + normalize (softmax denominator),
// then LayerNorm(28) + FFN(28->7)+ReLU+residual -> out (output 0),
// then Q2 (row-major, pre-scaled by (1/sqrt(7))*log2e for exp2 softmax)
// and K2 TRANSPOSED: K2T[b][d][s].
// ---------------------------------------------------------------------------
__global__ __launch_bounds__(256) void k_lnffn(
    const float4* __restrict__ Apart, const float* __restrict__ Lpart,
    const float* __restrict__ inp,
    const float* __restrict__ lnw, const float* __restrict__ lnb,
    const float* __restrict__ W1, const float* __restrict__ b1,
    const float* __restrict__ Wq2, const float* __restrict__ bq2,
    const float* __restrict__ Wk2, const float* __restrict__ bk2,
    float* __restrict__ outp, float* __restrict__ Q2, float* __restrict__ K2T)
{
    const int r = blockIdx.x * 256 + threadIdx.x;
    const int b = r >> 10, s = r & 1023;

    float y[NHID];
    float mu = 0.f;
    #pragma unroll
    for (int h = 0; h < NH; ++h) {
        const size_t base = ((size_t)(b * NH + h) << 10) + s;
        float4 a  = Apart[base];
        float  ll = Lpart[base];
        #pragma unroll
        for (int c = 1; c < 4; ++c) {
            float4 t = Apart[base + (size_t)c * CHUNK_STRIDE];
            a.x += t.x; a.y += t.y; a.z += t.z; a.w += t.w;
            ll += Lpart[base + (size_t)c * CHUNK_STRIDE];
        }
        const float inv = 1.f / ll;
        y[4 * h + 0] = a.x * inv; y[4 * h + 1] = a.y * inv;
        y[4 * h + 2] = a.z * inv; y[4 * h + 3] = a.w * inv;
        mu += (a.x + a.y + a.z + a.w) * inv;
    }
    mu *= (1.f / NHID);
    float var = 0.f;
    #pragma unroll
    for (int j = 0; j < NHID; ++j) { float d = y[j] - mu; var += d * d; }
    var *= (1.f / NHID);
    const float rstd = rsqrtf(var + 1e-5f);
    #pragma unroll
    for (int j = 0; j < NHID; ++j) y[j] = (y[j] - mu) * rstd * lnw[j] + lnb[j];

    float o[NIN];
    #pragma unroll
    for (int i = 0; i < NIN; ++i) {
        float a = b1[i];
        #pragma unroll
        for (int j = 0; j < NHID; ++j) a += y[j] * W1[j * NIN + i];
        o[i] = fmaxf(a, 0.f) + inp[r * NIN + i];
        outp[r * NIN + i] = o[i];
    }

    const float rs7l2e = 0.3779644730092272f * 1.4426950408889634f;  // (1/sqrt7)*log2e
    float* K2Tb = K2T + ((size_t)b * NHID) * SS + s;
    float4* Q2r = (float4*)Q2 + (size_t)r * 7;
    #pragma unroll
    for (int j4 = 0; j4 < 7; ++j4) {
        float qq[4];
        #pragma unroll
        for (int c = 0; c < 4; ++c) {
            int j = 4 * j4 + c;
            float aq = bq2[j], ak = bk2[j];
            #pragma unroll
            for (int i = 0; i < NIN; ++i) {
                aq += o[i] * Wq2[i * NHID + j];
                ak += o[i] * Wk2[i * NHID + j];
            }
            qq[c] = aq * rs7l2e;
            K2Tb[(size_t)j * SS] = ak;      // coalesced per-j
        }
        Q2r[j4] = make_float4(qq[0], qq[1], qq[2], qq[3]);
    }
}

// ---------------------------------------------------------------------------
// Kernel 4: attention 2 weights. Wave-autonomous, 4 rows/wave; dynamic
// 28-dim loop (q via LDS scalar broadcast) + __launch_bounds__(256,4)
// keeps VGPR at the 128 cap without spill (R6: total dropped 216->187).
// exp2 softmax (Q2 pre-scaled by log2e in k_lnffn).
// ---------------------------------------------------------------------------
#define QR 4
__global__ __launch_bounds__(256, 4) void k_attn2(
    const float* __restrict__ Q2, const float* __restrict__ K2T,
    float* __restrict__ out2)
{
    __shared__ float q2s[16 * NHID];   // 1792 B

    const int tid  = threadIdx.x;
    const int lane = tid & 63;
    const int wid  = tid >> 6;
    const int row0 = blockIdx.x * 16;          // global row = b*1024 + s
    const int b    = row0 >> 10;

    if (tid < 112) ((float4*)q2s)[tid] = ((const float4*)Q2)[(size_t)row0 * 7 + tid];
    __syncthreads();

    const float*  qw  = q2s + wid * QR * NHID;              // this wave's 4 rows
    const float4* K2b = (const float4*)(K2T + (size_t)b * NHID * SS);  // [28][256] f4

    float4 p0[QR], p1[QR], p2[QR], p3[QR];     // p[r][j]: 64 VGPRs
    #pragma unroll
    for (int r = 0; r < QR; ++r) {
        p0[r] = make_float4(0.f, 0.f, 0.f, 0.f);
        p1[r] = make_float4(0.f, 0.f, 0.f, 0.f);
        p2[r] = make_float4(0.f, 0.f, 0.f, 0.f);
        p3[r] = make_float4(0.f, 0.f, 0.f, 0.f);
    }

    #pragma unroll 2
    for (int d = 0; d < NHID; ++d) {
        float4 kt0 = K2b[d * 256 +       lane];
        float4 kt1 = K2b[d * 256 +  64 + lane];
        float4 kt2 = K2b[d * 256 + 128 + lane];
        float4 kt3 = K2b[d * 256 + 192 + lane];
        #pragma unroll
        for (int r = 0; r < QR; ++r) {
            const float qd = qw[r * NHID + d];  // LDS scalar broadcast
            p0[r].x += qd * kt0.x; p0[r].y += qd * kt0.y;
            p0[r].z += qd * kt0.z; p0[r].w += qd * kt0.w;
            p1[r].x += qd * kt1.x; p1[r].y += qd * kt1.y;
            p1[r].z += qd * kt1.z; p1[r].w += qd * kt1.w;
            p2[r].x += qd * kt2.x; p2[r].y += qd * kt2.y;
            p2[r].z += qd * kt2.z; p2[r].w += qd * kt2.w;
            p3[r].x += qd * kt3.x; p3[r].y += qd * kt3.y;
            p3[r].z += qd * kt3.z; p3[r].w += qd * kt3.w;
        }
    }

    #pragma unroll
    for (int r = 0; r < QR; ++r) {
        p0[r].x = EXP2F(p0[r].x); p0[r].y = EXP2F(p0[r].y);
        p0[r].z = EXP2F(p0[r].z); p0[r].w = EXP2F(p0[r].w);
        p1[r].x = EXP2F(p1[r].x); p1[r].y = EXP2F(p1[r].y);
        p1[r].z = EXP2F(p1[r].z); p1[r].w = EXP2F(p1[r].w);
        p2[r].x = EXP2F(p2[r].x); p2[r].y = EXP2F(p2[r].y);
        p2[r].z = EXP2F(p2[r].z); p2[r].w = EXP2F(p2[r].w);
        p3[r].x = EXP2F(p3[r].x); p3[r].y = EXP2F(p3[r].y);
        p3[r].z = EXP2F(p3[r].z); p3[r].w = EXP2F(p3[r].w);
        float sum = p0[r].x + p0[r].y + p0[r].z + p0[r].w
                  + p1[r].x + p1[r].y + p1[r].z + p1[r].w
                  + p2[r].x + p2[r].y + p2[r].z + p2[r].w
                  + p3[r].x + p3[r].y + p3[r].z + p3[r].w;
        #pragma unroll
        for (int off = 1; off < 64; off <<= 1) sum += __shfl_xor(sum, off);
        const float iv = 1.f / sum;
        float4* orow = (float4*)(out2 + ((size_t)row0 + wid * QR + r) * SS);
        orow[       lane] = make_float4(p0[r].x * iv, p0[r].y * iv, p0[r].z * iv, p0[r].w * iv);
        orow[ 64 + lane] = make_float4(p1[r].x * iv, p1[r].y * iv, p1[r].z * iv, p1[r].w * iv);
        orow[128 + lane] = make_float4(p2[r].x * iv, p2[r].y * iv, p2[r].z * iv, p2[r].w * iv);
        orow[192 + lane] = make_float4(p3[r].x * iv, p3[r].y * iv, p3[r].z * iv, p3[r].w * iv);
    }
}

// ---------------------------------------------------------------------------
extern "C" void kernel_launch(void* const* d_in, const int* in_sizes, int n_in,
                              void* d_out, int out_size, void* d_ws, size_t ws_size,
                              hipStream_t stream) {
    const float* inp = (const float*)d_in[0];
    const float* Wq  = (const float*)d_in[1];
    const float* bq  = (const float*)d_in[2];
    const float* Wk  = (const float*)d_in[3];
    const float* bk  = (const float*)d_in[4];
    const float* Wv  = (const float*)d_in[5];
    const float* bv  = (const float*)d_in[6];
    const float* lnw = (const float*)d_in[7];
    const float* lnb = (const float*)d_in[8];
    const float* W1  = (const float*)d_in[9];
    const float* b1  = (const float*)d_in[10];
    const float* Wq2 = (const float*)d_in[11];
    const float* bq2 = (const float*)d_in[12];
    const float* Wk2 = (const float*)d_in[13];
    const float* bk2 = (const float*)d_in[14];

    float* out0 = (float*)d_out;                 // [16,1024,7]
    float* out2 = out0 + ROWS * NIN;             // [16,1024,1024]

    // Split-K partials live in the out2 region (16.7M floats); k_attn2
    // overwrites it afterwards. Apart: 458752 float4 (=4*QKV_ELEMS floats),
    // Lpart: 458752 floats -> 2.29M floats total, fits easily.
    float4* Apart = (float4*)out2;
    float*  Lpart = out2 + (size_t)4 * QKV_ELEMS;

    float* ws = (float*)d_ws;
    float* Qo  = ws;
    float* Ko  = ws + (size_t)QKV_ELEMS;
    float* Vo  = ws + (size_t)2 * QKV_ELEMS;
    float* Q2  = ws + (size_t)3 * QKV_ELEMS;
    float* K2T = ws + (size_t)4 * QKV_ELEMS;     // [B,28,S]

    k_proj <<<ROWS / 256, 256, 0, stream>>>(inp, Wq, bq, Wk, bk, Wv, bv, Qo, Ko, Vo);
    k_attn1<<<BB * NH * 16, 512, 0, stream>>>(Qo, Ko, Vo, Apart, Lpart);
    k_lnffn<<<ROWS / 256, 256, 0, stream>>>(Apart, Lpart, inp, lnw, lnb, W1, b1,
                                            Wq2, bq2, Wk2, bk2, out0, Q2, K2T);
    k_attn2<<<ROWS / 16, 256, 0, stream>>>(Q2, K2T, out2);
}

// Round 4
// 174.486 us; speedup vs baseline: 1.4054x; 1.0063x over previous
//
#include <hip/hip_runtime.h>

// Problem constants (fixed by reference)
#define BB 16
#define SS 1024
#define NIN 7
#define NHID 28
#define NH 7
#define DH 4

// Raw 2^x (v_exp_f32). NOTE: __exp2f does NOT exist in HIP device code
// (R7 compile failure -- glibc math.h macro collision). exp(x) == exp2(x*log2e);
// the log2e factor is folded into the Q / Q2 projection scales.
#define EXP2F(x) __builtin_amdgcn_exp2f(x)

constexpr int ROWS = BB * SS;                 // 16384
constexpr int QKV_ELEMS = BB * NH * SS * DH;  // 458752 floats per tensor
constexpr int CHUNK_STRIDE = BB * NH * SS;    // 114688: per-ks-chunk stride (f4 / f1 units)

// ---------------------------------------------------------------------------
// Kernel 1 (fused, R4): attention 1 WITH in-block QKV projection.
//
// R3 post-mortem: split-K x4 got attn1 to <=45.8us (fills@47.5 now own the
// top-5 table). Cross-round accounting: total - attn1 is stable at 131-138us
// over four very different attn1 values (50/107/48.5/~42) -> ~110us of that
// gap is timed harness poison-fill + launch overhead (2x47.5us 264MB fills
// visible in the table), and only ~25us is proj+lnffn+attn2. So the
// controllable budget is attn1 (~42) + proj (~5) + attn2 (~15) + lnffn (~3).
//
// R4: delete k_proj entirely. Each block projects its own Q (256 queries,
// head h) and K/V (256 keys, head h) from inp: 2 x 7KB contiguous x-tiles
// + 480B of weight column-slices. 4x recompute redundancy = ~0.5us chip-
// wide VALU -- negligible vs the removed dispatch + 11MB HBM round-trip.
// FP order bit-identical to the old k_proj (bias init, i ascending, scale
// after), so absmax must stay exactly 0.0009765625.
//
// Structure after projection is R3's: 8 waves x 32-key slices, 4 q/thread,
// broadcast ds_read; in-block 8-slice merge; unnormalized per-(q,ks)
// partials to scratch in the out2 region (k_attn2 overwrites it later).
// LDS 40KB (phase1: K/V 8KB + xq/xk 14KB + w 0.4KB; phase2 overlay:
// pacc 32KB + pl 8KB) -> 4 blocks/CU (wave-cap limited anyway).
// ---------------------------------------------------------------------------
__global__ __launch_bounds__(512) void k_attn1(
    const float* __restrict__ inp,
    const float* __restrict__ Wq, const float* __restrict__ bq,
    const float* __restrict__ Wk, const float* __restrict__ bk,
    const float* __restrict__ Wv, const float* __restrict__ bv,
    float4* __restrict__ Apart, float* __restrict__ Lpart)
{
    __shared__ char smem[40960];
    float4* Ksh = (float4*)smem;              // [256]   4 KB (phase 1)
    float4* Vsh = (float4*)(smem + 4096);     // [256]   4 KB (phase 1)
    float*  xq  = (float*)(smem + 8192);      // [256*7] 7 KB (phase 1)
    float*  xk  = (float*)(smem + 15360);     // [256*7] 7 KB (phase 1)
    float4* wg  = (float4*)(smem + 22528);    // [24]: Wq(0..6) Wk(7..13) Wv(14..20) bq(21) bk(22) bv(23)
    float4* pacc = (float4*)smem;             // [8][256] 32 KB (phase 2 overlay)
    float*  pl   = (float*)(smem + 32768);    // [8][256]  8 KB

    const int bh  = blockIdx.x >> 4;          // 0..111
    const int qt  = (blockIdx.x >> 2) & 3;    // q tile (256 queries)
    const int ks  = blockIdx.x & 3;           // key chunk (256 keys)
    const int tid = threadIdx.x;
    const int b   = bh / NH, h = bh % NH;

    // ---- stage x tiles (2 x 448 float4, contiguous & 16B-aligned) + weights
    {
        const float4* xqg = (const float4*)(inp + (size_t)(b * SS + (qt << 8)) * NIN);
        const float4* xkg = (const float4*)(inp + (size_t)(b * SS + (ks << 8)) * NIN);
        if (tid < 448) {
            ((float4*)xq)[tid] = xqg[tid];
            ((float4*)xk)[tid] = xkg[tid];
        } else {
            const int t = tid - 448;          // 64 threads stage 24 float4
            if (t < 7)       wg[t] = ((const float4*)Wq)[t * NH + h];
            else if (t < 14) wg[t] = ((const float4*)Wk)[(t - 7) * NH + h];
            else if (t < 21) wg[t] = ((const float4*)Wv)[(t - 14) * NH + h];
            else if (t == 21) wg[21] = ((const float4*)bq)[h];
            else if (t == 22) wg[22] = ((const float4*)bk)[h];
            else if (t == 23) wg[23] = ((const float4*)bv)[h];
        }
    }
    __syncthreads();

    const int ql = tid & 63;
    const int kq = tid >> 6;          // wave id; uniform within wave

    // ---- per-thread Q projection for the 4 owned queries (bit-identical
    //      order to old k_proj: bias init, i ascending, scale last)
    const float qs_scale = 0.5f * 1.4426950408889634f;  // (1/sqrt(4)) * log2(e)
    float4 qv[4];
    #pragma unroll
    for (int r = 0; r < 4; ++r) {
        float4 a = wg[21];
        const float* xr = xq + (r * 64 + ql) * NIN;
        #pragma unroll
        for (int i = 0; i < NIN; ++i) {
            const float xi = xr[i];
            const float4 w = wg[i];
            a.x += xi * w.x; a.y += xi * w.y; a.z += xi * w.z; a.w += xi * w.w;
        }
        qv[r] = make_float4(a.x * qs_scale, a.y * qs_scale,
                            a.z * qs_scale, a.w * qs_scale);
    }

    // ---- cooperative K/V projection: threads 0-255 -> K, 256-511 -> V
    {
        const int half = tid >> 8;            // 0: K, 1: V
        const int key  = tid & 255;
        const float* xr = xk + key * NIN;
        const float4* wcol = wg + 7 + half * 7;
        float4 a = wg[22 + half];             // bk / bv
        #pragma unroll
        for (int i = 0; i < NIN; ++i) {
            const float xi = xr[i];
            const float4 w = wcol[i];
            a.x += xi * w.x; a.y += xi * w.y; a.z += xi * w.z; a.w += xi * w.w;
        }
        if (half == 0) Ksh[key] = a;
        else           Vsh[key] = a;
    }
    __syncthreads();

    float4 acc[4];
    float  l[4];
    #pragma unroll
    for (int r = 0; r < 4; ++r) { acc[r] = make_float4(0.f, 0.f, 0.f, 0.f); l[r] = 0.f; }

    const int k0 = kq << 5;
    #pragma unroll 4
    for (int kk = k0; kk < k0 + 32; ++kk) {
        float4 kr = Ksh[kk];          // single broadcast addr per wave
        float4 vr = Vsh[kk];
        #pragma unroll
        for (int r = 0; r < 4; ++r) {
            float s = qv[r].x * kr.x + qv[r].y * kr.y + qv[r].z * kr.z + qv[r].w * kr.w;
            float p = EXP2F(s);
            l[r] += p;
            acc[r].x += p * vr.x; acc[r].y += p * vr.y;
            acc[r].z += p * vr.z; acc[r].w += p * vr.w;
        }
    }

    __syncthreads();   // all K/V reads done; smem reused as merge buffers
    #pragma unroll
    for (int r = 0; r < 4; ++r) {
        pacc[kq * 256 + r * 64 + ql] = acc[r];
        pl[kq * 256 + r * 64 + ql]   = l[r];
    }
    __syncthreads();

    // merge the 8 k-slices: threads 0..255 own query qt*256 + tid
    if (tid < 256) {
        float4 a  = pacc[tid];
        float  ll = pl[tid];
        #pragma unroll
        for (int j = 1; j < 8; ++j) {
            float4 t = pacc[j * 256 + tid];
            a.x += t.x; a.y += t.y; a.z += t.z; a.w += t.w;
            ll += pl[j * 256 + tid];
        }
        // unnormalized partial for this 256-key chunk; coalesced in q
        const size_t o = ((size_t)(ks * (BB * NH) + bh) << 10) + (qt << 8) + tid;
        Apart[o] = a;
        Lpart[o] = ll;
    }
}

// ---------------------------------------------------------------------------
// Kernel 3: reduce the 4 split-K partials + normalize (softmax denominator),
// then LayerNorm(28) + FFN(28->7)+ReLU+residual -> out (output 0),
// then Q2 (row-major, pre-scaled by (1/sqrt(7))*log2e for exp2 softmax)
// and K2 TRANSPOSED: K2T[b][d][s].
// ---------------------------------------------------------------------------
__global__ __launch_bounds__(256) void k_lnffn(
    const float4* __restrict__ Apart, const float* __restrict__ Lpart,
    const float* __restrict__ inp,
    const float* __restrict__ lnw, const float* __restrict__ lnb,
    const float* __restrict__ W1, const float* __restrict__ b1,
    const float* __restrict__ Wq2, const float* __restrict__ bq2,
    const float* __restrict__ Wk2, const float* __restrict__ bk2,
    float* __restrict__ outp, float* __restrict__ Q2, float* __restrict__ K2T)
{
    const int r = blockIdx.x * 256 + threadIdx.x;
    const int b = r >> 10, s = r & 1023;

    float y[NHID];
    float mu = 0.f;
    #pragma unroll
    for (int h = 0; h < NH; ++h) {
        const size_t base = ((size_t)(b * NH + h) << 10) + s;
        float4 a  = Apart[base];
        float  ll = Lpart[base];
        #pragma unroll
        for (int c = 1; c < 4; ++c) {
            float4 t = Apart[base + (size_t)c * CHUNK_STRIDE];
            a.x += t.x; a.y += t.y; a.z += t.z; a.w += t.w;
            ll += Lpart[base + (size_t)c * CHUNK_STRIDE];
        }
        const float inv = 1.f / ll;
        y[4 * h + 0] = a.x * inv; y[4 * h + 1] = a.y * inv;
        y[4 * h + 2] = a.z * inv; y[4 * h + 3] = a.w * inv;
        mu += (a.x + a.y + a.z + a.w) * inv;
    }
    mu *= (1.f / NHID);
    float var = 0.f;
    #pragma unroll
    for (int j = 0; j < NHID; ++j) { float d = y[j] - mu; var += d * d; }
    var *= (1.f / NHID);
    const float rstd = rsqrtf(var + 1e-5f);
    #pragma unroll
    for (int j = 0; j < NHID; ++j) y[j] = (y[j] - mu) * rstd * lnw[j] + lnb[j];

    float o[NIN];
    #pragma unroll
    for (int i = 0; i < NIN; ++i) {
        float a = b1[i];
        #pragma unroll
        for (int j = 0; j < NHID; ++j) a += y[j] * W1[j * NIN + i];
        o[i] = fmaxf(a, 0.f) + inp[r * NIN + i];
        outp[r * NIN + i] = o[i];
    }

    const float rs7l2e = 0.3779644730092272f * 1.4426950408889634f;  // (1/sqrt7)*log2e
    float* K2Tb = K2T + ((size_t)b * NHID) * SS + s;
    float4* Q2r = (float4*)Q2 + (size_t)r * 7;
    #pragma unroll
    for (int j4 = 0; j4 < 7; ++j4) {
        float qq[4];
        #pragma unroll
        for (int c = 0; c < 4; ++c) {
            int j = 4 * j4 + c;
            float aq = bq2[j], ak = bk2[j];
            #pragma unroll
            for (int i = 0; i < NIN; ++i) {
                aq += o[i] * Wq2[i * NHID + j];
                ak += o[i] * Wk2[i * NHID + j];
            }
            qq[c] = aq * rs7l2e;
            K2Tb[(size_t)j * SS] = ak;      // coalesced per-j
        }
        Q2r[j4] = make_float4(qq[0], qq[1], qq[2], qq[3]);
    }
}

// ---------------------------------------------------------------------------
// Kernel 4: attention 2 weights. Wave-autonomous, 4 rows/wave; dynamic
// 28-dim loop (q via LDS scalar broadcast) + __launch_bounds__(256,4)
// keeps VGPR at the 128 cap without spill (R6: total dropped 216->187).
// exp2 softmax (Q2 pre-scaled by log2e in k_lnffn).
// ---------------------------------------------------------------------------
#define QR 4
__global__ __launch_bounds__(256, 4) void k_attn2(
    const float* __restrict__ Q2, const float* __restrict__ K2T,
    float* __restrict__ out2)
{
    __shared__ float q2s[16 * NHID];   // 1792 B

    const int tid  = threadIdx.x;
    const int lane = tid & 63;
    const int wid  = tid >> 6;
    const int row0 = blockIdx.x * 16;          // global row = b*1024 + s
    const int b    = row0 >> 10;

    if (tid < 112) ((float4*)q2s)[tid] = ((const float4*)Q2)[(size_t)row0 * 7 + tid];
    __syncthreads();

    const float*  qw  = q2s + wid * QR * NHID;              // this wave's 4 rows
    const float4* K2b = (const float4*)(K2T + (size_t)b * NHID * SS);  // [28][256] f4

    float4 p0[QR], p1[QR], p2[QR], p3[QR];     // p[r][j]: 64 VGPRs
    #pragma unroll
    for (int r = 0; r < QR; ++r) {
        p0[r] = make_float4(0.f, 0.f, 0.f, 0.f);
        p1[r] = make_float4(0.f, 0.f, 0.f, 0.f);
        p2[r] = make_float4(0.f, 0.f, 0.f, 0.f);
        p3[r] = make_float4(0.f, 0.f, 0.f, 0.f);
    }

    #pragma unroll 2
    for (int d = 0; d < NHID; ++d) {
        float4 kt0 = K2b[d * 256 +       lane];
        float4 kt1 = K2b[d * 256 +  64 + lane];
        float4 kt2 = K2b[d * 256 + 128 + lane];
        float4 kt3 = K2b[d * 256 + 192 + lane];
        #pragma unroll
        for (int r = 0; r < QR; ++r) {
            const float qd = qw[r * NHID + d];  // LDS scalar broadcast
            p0[r].x += qd * kt0.x; p0[r].y += qd * kt0.y;
            p0[r].z += qd * kt0.z; p0[r].w += qd * kt0.w;
            p1[r].x += qd * kt1.x; p1[r].y += qd * kt1.y;
            p1[r].z += qd * kt1.z; p1[r].w += qd * kt1.w;
            p2[r].x += qd * kt2.x; p2[r].y += qd * kt2.y;
            p2[r].z += qd * kt2.z; p2[r].w += qd * kt2.w;
            p3[r].x += qd * kt3.x; p3[r].y += qd * kt3.y;
            p3[r].z += qd * kt3.z; p3[r].w += qd * kt3.w;
        }
    }

    #pragma unroll
    for (int r = 0; r < QR; ++r) {
        p0[r].x = EXP2F(p0[r].x); p0[r].y = EXP2F(p0[r].y);
        p0[r].z = EXP2F(p0[r].z); p0[r].w = EXP2F(p0[r].w);
        p1[r].x = EXP2F(p1[r].x); p1[r].y = EXP2F(p1[r].y);
        p1[r].z = EXP2F(p1[r].z); p1[r].w = EXP2F(p1[r].w);
        p2[r].x = EXP2F(p2[r].x); p2[r].y = EXP2F(p2[r].y);
        p2[r].z = EXP2F(p2[r].z); p2[r].w = EXP2F(p2[r].w);
        p3[r].x = EXP2F(p3[r].x); p3[r].y = EXP2F(p3[r].y);
        p3[r].z = EXP2F(p3[r].z); p3[r].w = EXP2F(p3[r].w);
        float sum = p0[r].x + p0[r].y + p0[r].z + p0[r].w
                  + p1[r].x + p1[r].y + p1[r].z + p1[r].w
                  + p2[r].x + p2[r].y + p2[r].z + p2[r].w
                  + p3[r].x + p3[r].y + p3[r].z + p3[r].w;
        #pragma unroll
        for (int off = 1; off < 64; off <<= 1) sum += __shfl_xor(sum, off);
        const float iv = 1.f / sum;
        float4* orow = (float4*)(out2 + ((size_t)row0 + wid * QR + r) * SS);
        orow[       lane] = make_float4(p0[r].x * iv, p0[r].y * iv, p0[r].z * iv, p0[r].w * iv);
        orow[ 64 + lane] = make_float4(p1[r].x * iv, p1[r].y * iv, p1[r].z * iv, p1[r].w * iv);
        orow[128 + lane] = make_float4(p2[r].x * iv, p2[r].y * iv, p2[r].z * iv, p2[r].w * iv);
        orow[192 + lane] = make_float4(p3[r].x * iv, p3[r].y * iv, p3[r].z * iv, p3[r].w * iv);
    }
}

// ---------------------------------------------------------------------------
extern "C" void kernel_launch(void* const* d_in, const int* in_sizes, int n_in,
                              void* d_out, int out_size, void* d_ws, size_t ws_size,
                              hipStream_t stream) {
    const float* inp = (const float*)d_in[0];
    const float* Wq  = (const float*)d_in[1];
    const float* bq  = (const float*)d_in[2];
    const float* Wk  = (const float*)d_in[3];
    const float* bk  = (const float*)d_in[4];
    const float* Wv  = (const float*)d_in[5];
    const float* bv  = (const float*)d_in[6];
    const float* lnw = (const float*)d_in[7];
    const float* lnb = (const float*)d_in[8];
    const float* W1  = (const float*)d_in[9];
    const float* b1  = (const float*)d_in[10];
    const float* Wq2 = (const float*)d_in[11];
    const float* bq2 = (const float*)d_in[12];
    const float* Wk2 = (const float*)d_in[13];
    const float* bk2 = (const float*)d_in[14];

    float* out0 = (float*)d_out;                 // [16,1024,7]
    float* out2 = out0 + ROWS * NIN;             // [16,1024,1024]

    // Split-K partials live in the out2 region (16.7M floats); k_attn2
    // overwrites it afterwards. Apart: 458752 float4 (=4*QKV_ELEMS floats),
    // Lpart: 458752 floats -> 2.29M floats total, fits easily.
    float4* Apart = (float4*)out2;
    float*  Lpart = out2 + (size_t)4 * QKV_ELEMS;

    float* ws = (float*)d_ws;
    float* Q2  = ws;
    float* K2T = ws + (size_t)QKV_ELEMS;         // [B,28,S]

    k_attn1<<<BB * NH * 16, 512, 0, stream>>>(inp, Wq, bq, Wk, bk, Wv, bv,
                                              Apart, Lpart);
    k_lnffn<<<ROWS / 256, 256, 0, stream>>>(Apart, Lpart, inp, lnw, lnb, W1, b1,
                                            Wq2, bq2, Wk2, bk2, out0, Q2, K2T);
    k_attn2<<<ROWS / 16, 256, 0, stream>>>(Q2, K2T, out2);
}

// Round 5
// 172.026 us; speedup vs baseline: 1.4255x; 1.0143x over previous
//
#include <hip/hip_runtime.h>

// Problem constants (fixed by reference)
#define BB 16
#define SS 1024
#define NIN 7
#define NHID 28
#define NH 7
#define DH 4

// Raw 2^x (v_exp_f32). NOTE: __exp2f does NOT exist in HIP device code
// (R7 compile failure -- glibc math.h macro collision). exp(x) == exp2(x*log2e);
// the log2e factor is folded into the Q / Q2 projection scales.
#define EXP2F(x) __builtin_amdgcn_exp2f(x)

// Packed fp32 (VOP3P v_pk_mul_f32 / v_pk_fma_f32). MI355X's 157.3 TF fp32
// peak is 2x the scalar-issue ceiling (m07) -- reachable only via packed.
typedef float v2f __attribute__((ext_vector_type(2)));
__device__ __forceinline__ v2f pkfma(v2f a, v2f b, v2f c) {
    return __builtin_elementwise_fma(a, b, c);
}
__device__ __forceinline__ v2f lo2(float4 a) { v2f r; r.x = a.x; r.y = a.y; return r; }
__device__ __forceinline__ v2f hi2(float4 a) { v2f r; r.x = a.z; r.y = a.w; return r; }
__device__ __forceinline__ v2f splat2(float s) { v2f r; r.x = s; r.y = s; return r; }

constexpr int ROWS = BB * SS;                 // 16384
constexpr int QKV_ELEMS = BB * NH * SS * DH;  // 458752 floats per tensor
constexpr int CHUNK_STRIDE = BB * NH * SS;    // 114688: per-ks-chunk stride (f4 / f1 units)

// ---------------------------------------------------------------------------
// Kernel 1 (fused): attention 1 WITH in-block QKV projection.
//
// R4 post-mortem: fusion was a wash (-1.1us): attn1 absorbed ~5us of busy
// (projection redundancy) = what the deleted k_proj dispatch cost. attn1 is
// now cleanly VALU-ISSUE-bound (VALUBusy 68.8%, HBM 2.6%, conflicts 0).
//
// R5: packed fp32. All component-pair math moves to v_pk_mul/v_pk_fma via
// ext_vector(2) + __builtin_elementwise_fma: inner loop 9 VALU + 1 exp per
// pair -> 5 VALU + 1 exp; projections and merge also packed. All
// accumulator packings preserve per-component op order (bit-identical);
// ONLY the QK dot's horizontal reduction changes association
// (fma chain -> fma-pair + add, ~1ulp on scores). R2->R3's much larger
// reorder left absmax bit-identical, so this is safe margin-wise.
//
// Structure: split-K x4, grid = 112 bh x 4 qt x 4 ks = 1792 == 7/CU.
// 8 waves x 32-key slices, 4 q/thread, broadcast ds_read; in-block 8-slice
// merge; unnormalized per-(q,ks) partials to scratch in the out2 region
// (k_attn2 overwrites it later). LDS 40KB.
// ---------------------------------------------------------------------------
__global__ __launch_bounds__(512) void k_attn1(
    const float* __restrict__ inp,
    const float* __restrict__ Wq, const float* __restrict__ bq,
    const float* __restrict__ Wk, const float* __restrict__ bk,
    const float* __restrict__ Wv, const float* __restrict__ bv,
    float4* __restrict__ Apart, float* __restrict__ Lpart)
{
    __shared__ char smem[40960];
    float4* Ksh = (float4*)smem;              // [256]   4 KB (phase 1)
    float4* Vsh = (float4*)(smem + 4096);     // [256]   4 KB (phase 1)
    float*  xq  = (float*)(smem + 8192);      // [256*7] 7 KB (phase 1)
    float*  xk  = (float*)(smem + 15360);     // [256*7] 7 KB (phase 1)
    float4* wg  = (float4*)(smem + 22528);    // [24]: Wq(0..6) Wk(7..13) Wv(14..20) bq(21) bk(22) bv(23)
    float4* pacc = (float4*)smem;             // [8][256] 32 KB (phase 2 overlay)
    float*  pl   = (float*)(smem + 32768);    // [8][256]  8 KB

    const int bh  = blockIdx.x >> 4;          // 0..111
    const int qt  = (blockIdx.x >> 2) & 3;    // q tile (256 queries)
    const int ks  = blockIdx.x & 3;           // key chunk (256 keys)
    const int tid = threadIdx.x;
    const int b   = bh / NH, h = bh % NH;

    // ---- stage x tiles (2 x 448 float4, contiguous & 16B-aligned) + weights
    {
        const float4* xqg = (const float4*)(inp + (size_t)(b * SS + (qt << 8)) * NIN);
        const float4* xkg = (const float4*)(inp + (size_t)(b * SS + (ks << 8)) * NIN);
        if (tid < 448) {
            ((float4*)xq)[tid] = xqg[tid];
            ((float4*)xk)[tid] = xkg[tid];
        } else {
            const int t = tid - 448;          // 64 threads stage 24 float4
            if (t < 7)       wg[t] = ((const float4*)Wq)[t * NH + h];
            else if (t < 14) wg[t] = ((const float4*)Wk)[(t - 7) * NH + h];
            else if (t < 21) wg[t] = ((const float4*)Wv)[(t - 14) * NH + h];
            else if (t == 21) wg[21] = ((const float4*)bq)[h];
            else if (t == 22) wg[22] = ((const float4*)bk)[h];
            else if (t == 23) wg[23] = ((const float4*)bv)[h];
        }
    }
    __syncthreads();

    const int ql = tid & 63;
    const int kq = tid >> 6;          // wave id; uniform within wave

    // ---- per-thread Q projection for the 4 owned queries (packed; per-
    //      component fma order identical to scalar -> bit-identical)
    const float qs_scale = 0.5f * 1.4426950408889634f;  // (1/sqrt(4)) * log2(e)
    const v2f qs2 = splat2(qs_scale);
    v2f qlo[4], qhi[4];
    #pragma unroll
    for (int r = 0; r < 4; ++r) {
        const float4 bias = wg[21];
        v2f alo = lo2(bias), ahi = hi2(bias);
        const float* xr = xq + (r * 64 + ql) * NIN;
        #pragma unroll
        for (int i = 0; i < NIN; ++i) {
            const v2f xi2 = splat2(xr[i]);
            const float4 w = wg[i];
            alo = pkfma(xi2, lo2(w), alo);
            ahi = pkfma(xi2, hi2(w), ahi);
        }
        qlo[r] = alo * qs2;
        qhi[r] = ahi * qs2;
    }

    // ---- cooperative K/V projection: threads 0-255 -> K, 256-511 -> V
    {
        const int half = tid >> 8;            // 0: K, 1: V
        const int key  = tid & 255;
        const float* xr = xk + key * NIN;
        const float4* wcol = wg + 7 + half * 7;
        const float4 bias = wg[22 + half];    // bk / bv
        v2f alo = lo2(bias), ahi = hi2(bias);
        #pragma unroll
        for (int i = 0; i < NIN; ++i) {
            const v2f xi2 = splat2(xr[i]);
            const float4 w = wcol[i];
            alo = pkfma(xi2, lo2(w), alo);
            ahi = pkfma(xi2, hi2(w), ahi);
        }
        const float4 kv = make_float4(alo.x, alo.y, ahi.x, ahi.y);
        if (half == 0) Ksh[key] = kv;
        else           Vsh[key] = kv;
    }
    __syncthreads();

    v2f alo[4], ahi[4];
    float l[4];
    #pragma unroll
    for (int r = 0; r < 4; ++r) {
        alo[r] = splat2(0.f); ahi[r] = splat2(0.f); l[r] = 0.f;
    }

    const int k0 = kq << 5;
    #pragma unroll 4
    for (int kk = k0; kk < k0 + 32; ++kk) {
        const float4 kr = Ksh[kk];    // single broadcast addr per wave
        const float4 vr = Vsh[kk];
        const v2f klo = lo2(kr), khi = hi2(kr);
        const v2f vlo = lo2(vr), vhi = hi2(vr);
        #pragma unroll
        for (int r = 0; r < 4; ++r) {
            v2f t = qlo[r] * klo;             // v_pk_mul_f32
            t = pkfma(qhi[r], khi, t);        // v_pk_fma_f32
            const float s = t.x + t.y;        // (only assoc. change vs R4)
            const float p = EXP2F(s);
            l[r] += p;
            const v2f pp = splat2(p);
            alo[r] = pkfma(pp, vlo, alo[r]);  // per-comp order == scalar
            ahi[r] = pkfma(pp, vhi, ahi[r]);
        }
    }

    __syncthreads();   // all K/V reads done; smem reused as merge buffers
    #pragma unroll
    for (int r = 0; r < 4; ++r) {
        pacc[kq * 256 + r * 64 + ql] = make_float4(alo[r].x, alo[r].y,
                                                   ahi[r].x, ahi[r].y);
        pl[kq * 256 + r * 64 + ql]   = l[r];
    }
    __syncthreads();

    // merge the 8 k-slices: threads 0..255 own query qt*256 + tid
    if (tid < 256) {
        float4 a0 = pacc[tid];
        v2f mlo = lo2(a0), mhi = hi2(a0);
        float ll = pl[tid];
        #pragma unroll
        for (int j = 1; j < 8; ++j) {
            const float4 t = pacc[j * 256 + tid];
            mlo = mlo + lo2(t);               // v_pk_add_f32, per-comp order
            mhi = mhi + hi2(t);
            ll += pl[j * 256 + tid];
        }
        // unnormalized partial for this 256-key chunk; coalesced in q
        const size_t o = ((size_t)(ks * (BB * NH) + bh) << 10) + (qt << 8) + tid;
        Apart[o] = make_float4(mlo.x, mlo.y, mhi.x, mhi.y);
        Lpart[o] = ll;
    }
}

// ---------------------------------------------------------------------------
// Kernel 3: reduce the 4 split-K partials + normalize (softmax denominator),
// then LayerNorm(28) + FFN(28->7)+ReLU+residual -> out (output 0),
// then Q2 (row-major, pre-scaled by (1/sqrt(7))*log2e for exp2 softmax)
// and K2 TRANSPOSED: K2T[b][d][s].
// ---------------------------------------------------------------------------
__global__ __launch_bounds__(256) void k_lnffn(
    const float4* __restrict__ Apart, const float* __restrict__ Lpart,
    const float* __restrict__ inp,
    const float* __restrict__ lnw, const float* __restrict__ lnb,
    const float* __restrict__ W1, const float* __restrict__ b1,
    const float* __restrict__ Wq2, const float* __restrict__ bq2,
    const float* __restrict__ Wk2, const float* __restrict__ bk2,
    float* __restrict__ outp, float* __restrict__ Q2, float* __restrict__ K2T)
{
    const int r = blockIdx.x * 256 + threadIdx.x;
    const int b = r >> 10, s = r & 1023;

    float y[NHID];
    float mu = 0.f;
    #pragma unroll
    for (int h = 0; h < NH; ++h) {
        const size_t base = ((size_t)(b * NH + h) << 10) + s;
        float4 a  = Apart[base];
        float  ll = Lpart[base];
        #pragma unroll
        for (int c = 1; c < 4; ++c) {
            float4 t = Apart[base + (size_t)c * CHUNK_STRIDE];
            a.x += t.x; a.y += t.y; a.z += t.z; a.w += t.w;
            ll += Lpart[base + (size_t)c * CHUNK_STRIDE];
        }
        const float inv = 1.f / ll;
        y[4 * h + 0] = a.x * inv; y[4 * h + 1] = a.y * inv;
        y[4 * h + 2] = a.z * inv; y[4 * h + 3] = a.w * inv;
        mu += (a.x + a.y + a.z + a.w) * inv;
    }
    mu *= (1.f / NHID);
    float var = 0.f;
    #pragma unroll
    for (int j = 0; j < NHID; ++j) { float d = y[j] - mu; var += d * d; }
    var *= (1.f / NHID);
    const float rstd = rsqrtf(var + 1e-5f);
    #pragma unroll
    for (int j = 0; j < NHID; ++j) y[j] = (y[j] - mu) * rstd * lnw[j] + lnb[j];

    float o[NIN];
    #pragma unroll
    for (int i = 0; i < NIN; ++i) {
        float a = b1[i];
        #pragma unroll
        for (int j = 0; j < NHID; ++j) a += y[j] * W1[j * NIN + i];
        o[i] = fmaxf(a, 0.f) + inp[r * NIN + i];
        outp[r * NIN + i] = o[i];
    }

    const float rs7l2e = 0.3779644730092272f * 1.4426950408889634f;  // (1/sqrt7)*log2e
    float* K2Tb = K2T + ((size_t)b * NHID) * SS + s;
    float4* Q2r = (float4*)Q2 + (size_t)r * 7;
    #pragma unroll
    for (int j4 = 0; j4 < 7; ++j4) {
        float qq[4];
        #pragma unroll
        for (int c = 0; c < 4; ++c) {
            int j = 4 * j4 + c;
            float aq = bq2[j], ak = bk2[j];
            #pragma unroll
            for (int i = 0; i < NIN; ++i) {
                aq += o[i] * Wq2[i * NHID + j];
                ak += o[i] * Wk2[i * NHID + j];
            }
            qq[c] = aq * rs7l2e;
            K2Tb[(size_t)j * SS] = ak;      // coalesced per-j
        }
        Q2r[j4] = make_float4(qq[0], qq[1], qq[2], qq[3]);
    }
}

// ---------------------------------------------------------------------------
// Kernel 4: attention 2 weights. Wave-autonomous, 4 rows/wave; dynamic
// 28-dim loop (q via LDS scalar broadcast) + __launch_bounds__(256,4).
// R5: inner accumulators packed (16 fma -> 8 pk_fma per r,d); per-component
// accumulation order preserved -> bit-identical. exp2 softmax (Q2
// pre-scaled by log2e in k_lnffn); sum chain order unchanged.
// ---------------------------------------------------------------------------
#define QR 4
__global__ __launch_bounds__(256, 4) void k_attn2(
    const float* __restrict__ Q2, const float* __restrict__ K2T,
    float* __restrict__ out2)
{
    __shared__ float q2s[16 * NHID];   // 1792 B

    const int tid  = threadIdx.x;
    const int lane = tid & 63;
    const int wid  = tid >> 6;
    const int row0 = blockIdx.x * 16;          // global row = b*1024 + s
    const int b    = row0 >> 10;

    if (tid < 112) ((float4*)q2s)[tid] = ((const float4*)Q2)[(size_t)row0 * 7 + tid];
    __syncthreads();

    const float*  qw  = q2s + wid * QR * NHID;              // this wave's 4 rows
    const float4* K2b = (const float4*)(K2T + (size_t)b * NHID * SS);  // [28][256] f4

    v2f plo[4][QR], phi[4][QR];    // [col-block][row]: 64 VGPRs total
    #pragma unroll
    for (int cb = 0; cb < 4; ++cb)
        #pragma unroll
        for (int r = 0; r < QR; ++r) { plo[cb][r] = splat2(0.f); phi[cb][r] = splat2(0.f); }

    #pragma unroll 2
    for (int d = 0; d < NHID; ++d) {
        const float4 kt0 = K2b[d * 256 +       lane];
        const float4 kt1 = K2b[d * 256 +  64 + lane];
        const float4 kt2 = K2b[d * 256 + 128 + lane];
        const float4 kt3 = K2b[d * 256 + 192 + lane];
        const v2f k0l = lo2(kt0), k0h = hi2(kt0);
        const v2f k1l = lo2(kt1), k1h = hi2(kt1);
        const v2f k2l = lo2(kt2), k2h = hi2(kt2);
        const v2f k3l = lo2(kt3), k3h = hi2(kt3);
        #pragma unroll
        for (int r = 0; r < QR; ++r) {
            const v2f qd2 = splat2(qw[r * NHID + d]);  // LDS scalar broadcast
            plo[0][r] = pkfma(qd2, k0l, plo[0][r]); phi[0][r] = pkfma(qd2, k0h, phi[0][r]);
            plo[1][r] = pkfma(qd2, k1l, plo[1][r]); phi[1][r] = pkfma(qd2, k1h, phi[1][r]);
            plo[2][r] = pkfma(qd2, k2l, plo[2][r]); phi[2][r] = pkfma(qd2, k2h, phi[2][r]);
            plo[3][r] = pkfma(qd2, k3l, plo[3][r]); phi[3][r] = pkfma(qd2, k3h, phi[3][r]);
        }
    }

    #pragma unroll
    for (int r = 0; r < QR; ++r) {
        #pragma unroll
        for (int cb = 0; cb < 4; ++cb) {
            plo[cb][r].x = EXP2F(plo[cb][r].x); plo[cb][r].y = EXP2F(plo[cb][r].y);
            phi[cb][r].x = EXP2F(phi[cb][r].x); phi[cb][r].y = EXP2F(phi[cb][r].y);
        }
        // same left-assoc chain order as before (lo.x, lo.y, hi.x, hi.y per cb)
        float sum = plo[0][r].x + plo[0][r].y + phi[0][r].x + phi[0][r].y
                  + plo[1][r].x + plo[1][r].y + phi[1][r].x + phi[1][r].y
                  + plo[2][r].x + plo[2][r].y + phi[2][r].x + phi[2][r].y
                  + plo[3][r].x + plo[3][r].y + phi[3][r].x + phi[3][r].y;
        #pragma unroll
        for (int off = 1; off < 64; off <<= 1) sum += __shfl_xor(sum, off);
        const float iv = 1.f / sum;
        float4* orow = (float4*)(out2 + ((size_t)row0 + wid * QR + r) * SS);
        #pragma unroll
        for (int cb = 0; cb < 4; ++cb)
            orow[cb * 64 + lane] = make_float4(plo[cb][r].x * iv, plo[cb][r].y * iv,
                                               phi[cb][r].x * iv, phi[cb][r].y * iv);
    }
}

// ---------------------------------------------------------------------------
extern "C" void kernel_launch(void* const* d_in, const int* in_sizes, int n_in,
                              void* d_out, int out_size, void* d_ws, size_t ws_size,
                              hipStream_t stream) {
    const float* inp = (const float*)d_in[0];
    const float* Wq  = (const float*)d_in[1];
    const float* bq  = (const float*)d_in[2];
    const float* Wk  = (const float*)d_in[3];
    const float* bk  = (const float*)d_in[4];
    const float* Wv  = (const float*)d_in[5];
    const float* bv  = (const float*)d_in[6];
    const float* lnw = (const float*)d_in[7];
    const float* lnb = (const float*)d_in[8];
    const float* W1  = (const float*)d_in[9];
    const float* b1  = (const float*)d_in[10];
    const float* Wq2 = (const float*)d_in[11];
    const float* bq2 = (const float*)d_in[12];
    const float* Wk2 = (const float*)d_in[13];
    const float* bk2 = (const float*)d_in[14];

    float* out0 = (float*)d_out;                 // [16,1024,7]
    float* out2 = out0 + ROWS * NIN;             // [16,1024,1024]

    // Split-K partials live in the out2 region (16.7M floats); k_attn2
    // overwrites it afterwards. Apart: 458752 float4 (=4*QKV_ELEMS floats),
    // Lpart: 458752 floats -> 2.29M floats total, fits easily.
    float4* Apart = (float4*)out2;
    float*  Lpart = out2 + (size_t)4 * QKV_ELEMS;

    float* ws = (float*)d_ws;
    float* Q2  = ws;
    float* K2T = ws + (size_t)QKV_ELEMS;         // [B,28,S]

    k_attn1<<<BB * NH * 16, 512, 0, stream>>>(inp, Wq, bq, Wk, bk, Wv, bv,
                                              Apart, Lpart);
    k_lnffn<<<ROWS / 256, 256, 0, stream>>>(Apart, Lpart, inp, lnw, lnb, W1, b1,
                                            Wq2, bq2, Wk2, bk2, out0, Q2, K2T);
    k_attn2<<<ROWS / 16, 256, 0, stream>>>(Q2, K2T, out2);
}

// Round 6
// 167.880 us; speedup vs baseline: 1.4607x; 1.0247x over previous
//
#include <hip/hip_runtime.h>

// Problem constants (fixed by reference)
#define BB 16
#define SS 1024
#define NIN 7
#define NHID 28
#define NH 7
#define DH 4

// Raw 2^x (v_exp_f32). NOTE: __exp2f does NOT exist in HIP device code
// (R7 compile failure -- glibc math.h macro collision). exp(x) == exp2(x*log2e);
// the log2e factor is folded into the Q / Q2 projection scales.
#define EXP2F(x) __builtin_amdgcn_exp2f(x)

// Packed fp32 (VOP3P v_pk_mul_f32 / v_pk_fma_f32). MI355X's 157.3 TF fp32
// peak is 2x the scalar-issue ceiling (m07) -- reachable only via packed.
typedef float v2f __attribute__((ext_vector_type(2)));
__device__ __forceinline__ v2f pkfma(v2f a, v2f b, v2f c) {
    return __builtin_elementwise_fma(a, b, c);
}
__device__ __forceinline__ v2f lo2(float4 a) { v2f r; r.x = a.x; r.y = a.y; return r; }
__device__ __forceinline__ v2f hi2(float4 a) { v2f r; r.x = a.z; r.y = a.w; return r; }
__device__ __forceinline__ v2f splat2(float s) { v2f r; r.x = s; r.y = s; return r; }

constexpr int ROWS = BB * SS;                 // 16384
constexpr int QKV_ELEMS = BB * NH * SS * DH;  // 458752 floats per tensor
constexpr int CHUNK_STRIDE = BB * NH * SS;    // 114688: per-ks-chunk stride (f4 / f1 units)

// ---------------------------------------------------------------------------
// Kernel 1 (fused): attention 1 WITH in-block QKV projection.
//
// R5 post-mortem: packed fp32 got attn1 under the 45us poison-fills.
// Remaining ~44us decomposes as ~11-14us inner compute + ~30us structure
// (x/weight staging, 4 barriers, 35 LDS x-reads/thread, merge).
//
// R6: delete the staging pipeline around the compute core.
//  - Weights/biases: block-uniform indices -> compiler emits s_load into
//    SGPRs (one-time prologue; NOT R1's per-iteration dependent s_loads).
//    pk_fma uses the scalar pair as its one legal SGPR operand.
//  - x rows: read directly from global (L1/L2-hot, 25 MB aggregate) in
//    the Q and K/V projection loops. Removes the 448-thread stage, one
//    __syncthreads, and all 35 per-thread LDS x-reads.
//  - LDS phase 1 is just K/V (8 KB); merge overlay unchanged; 3 barriers.
// NO arithmetic-order change anywhere -> absmax must stay exactly
// 0.001953125 (R5 value; dot re-association already accounted there).
//
// Structure: split-K x4, grid = 112 bh x 4 qt x 4 ks = 1792 == 7/CU.
// 8 waves x 32-key slices, 4 q/thread, broadcast ds_read; in-block 8-slice
// merge; unnormalized per-(q,ks) partials to scratch in the out2 region
// (k_attn2 overwrites it later).
// ---------------------------------------------------------------------------
__global__ __launch_bounds__(512) void k_attn1(
    const float* __restrict__ inp,
    const float* __restrict__ Wq, const float* __restrict__ bq,
    const float* __restrict__ Wk, const float* __restrict__ bk,
    const float* __restrict__ Wv, const float* __restrict__ bv,
    float4* __restrict__ Apart, float* __restrict__ Lpart)
{
    __shared__ char smem[40960];
    float4* Ksh  = (float4*)smem;             // [256]   4 KB (phase 1)
    float4* Vsh  = (float4*)(smem + 4096);    // [256]   4 KB (phase 1)
    float4* pacc = (float4*)smem;             // [8][256] 32 KB (phase 2 overlay)
    float*  pl   = (float*)(smem + 32768);    // [8][256]  8 KB

    const int bh  = blockIdx.x >> 4;          // 0..111
    const int qt  = (blockIdx.x >> 2) & 3;    // q tile (256 queries)
    const int ks  = blockIdx.x & 3;           // key chunk (256 keys)
    const int tid = threadIdx.x;
    const int b   = bh / NH, h = bh % NH;

    const int ql = tid & 63;
    const int kq = tid >> 6;          // wave id; uniform within wave

    // ---- cooperative K/V projection straight from global x (L1/L2-hot):
    //      threads 0-255 -> K key tid, threads 256-511 -> V key tid-256.
    //      Weight/bias indices are block-uniform -> s_load (SGPR).
    {
        const int half = __builtin_amdgcn_readfirstlane(tid >> 8);  // 0:K 1:V
        const int key  = tid & 255;
        const float* xr = inp + (size_t)(b * SS + (ks << 8) + key) * NIN;
        const float* W  = half ? Wv : Wk;
        const float4 bias = ((const float4*)(half ? bv : bk))[h];
        v2f alo = lo2(bias), ahi = hi2(bias);
        #pragma unroll
        for (int i = 0; i < NIN; ++i) {
            const v2f xi2 = splat2(xr[i]);
            const float4 w = ((const float4*)W)[i * NH + h];   // uniform -> SGPR
            alo = pkfma(xi2, lo2(w), alo);
            ahi = pkfma(xi2, hi2(w), ahi);
        }
        const float4 kv = make_float4(alo.x, alo.y, ahi.x, ahi.y);
        if (half == 0) Ksh[key] = kv;
        else           Vsh[key] = kv;
    }

    // ---- per-thread Q projection for the 4 owned queries (independent of
    //      LDS; overlaps the K/V LDS writes). Same fma order as before.
    const float qs_scale = 0.5f * 1.4426950408889634f;  // (1/sqrt(4)) * log2(e)
    const v2f qs2 = splat2(qs_scale);
    const float4 bq4 = ((const float4*)bq)[h];           // uniform -> SGPR
    v2f qlo[4], qhi[4];
    #pragma unroll
    for (int r = 0; r < 4; ++r) {
        const float* xr = inp + (size_t)(b * SS + (qt << 8) + r * 64 + ql) * NIN;
        v2f alo = lo2(bq4), ahi = hi2(bq4);
        #pragma unroll
        for (int i = 0; i < NIN; ++i) {
            const v2f xi2 = splat2(xr[i]);
            const float4 w = ((const float4*)Wq)[i * NH + h]; // uniform -> SGPR
            alo = pkfma(xi2, lo2(w), alo);
            ahi = pkfma(xi2, hi2(w), ahi);
        }
        qlo[r] = alo * qs2;
        qhi[r] = ahi * qs2;
    }
    __syncthreads();   // K/V visible to all waves

    v2f alo[4], ahi[4];
    float l[4];
    #pragma unroll
    for (int r = 0; r < 4; ++r) {
        alo[r] = splat2(0.f); ahi[r] = splat2(0.f); l[r] = 0.f;
    }

    const int k0 = kq << 5;
    #pragma unroll 4
    for (int kk = k0; kk < k0 + 32; ++kk) {
        const float4 kr = Ksh[kk];    // single broadcast addr per wave
        const float4 vr = Vsh[kk];
        const v2f klo = lo2(kr), khi = hi2(kr);
        const v2f vlo = lo2(vr), vhi = hi2(vr);
        #pragma unroll
        for (int r = 0; r < 4; ++r) {
            v2f t = qlo[r] * klo;             // v_pk_mul_f32
            t = pkfma(qhi[r], khi, t);        // v_pk_fma_f32
            const float s = t.x + t.y;
            const float p = EXP2F(s);
            l[r] += p;
            const v2f pp = splat2(p);
            alo[r] = pkfma(pp, vlo, alo[r]);
            ahi[r] = pkfma(pp, vhi, ahi[r]);
        }
    }

    __syncthreads();   // all K/V reads done; smem reused as merge buffers
    #pragma unroll
    for (int r = 0; r < 4; ++r) {
        pacc[kq * 256 + r * 64 + ql] = make_float4(alo[r].x, alo[r].y,
                                                   ahi[r].x, ahi[r].y);
        pl[kq * 256 + r * 64 + ql]   = l[r];
    }
    __syncthreads();

    // merge the 8 k-slices: threads 0..255 own query qt*256 + tid
    if (tid < 256) {
        float4 a0 = pacc[tid];
        v2f mlo = lo2(a0), mhi = hi2(a0);
        float ll = pl[tid];
        #pragma unroll
        for (int j = 1; j < 8; ++j) {
            const float4 t = pacc[j * 256 + tid];
            mlo = mlo + lo2(t);               // v_pk_add_f32, per-comp order
            mhi = mhi + hi2(t);
            ll += pl[j * 256 + tid];
        }
        // unnormalized partial for this 256-key chunk; coalesced in q
        const size_t o = ((size_t)(ks * (BB * NH) + bh) << 10) + (qt << 8) + tid;
        Apart[o] = make_float4(mlo.x, mlo.y, mhi.x, mhi.y);
        Lpart[o] = ll;
    }
}

// ---------------------------------------------------------------------------
// Kernel 3: reduce the 4 split-K partials + normalize (softmax denominator),
// then LayerNorm(28) + FFN(28->7)+ReLU+residual -> out (output 0),
// then Q2 (row-major, pre-scaled by (1/sqrt(7))*log2e for exp2 softmax)
// and K2 TRANSPOSED: K2T[b][d][s].
// ---------------------------------------------------------------------------
__global__ __launch_bounds__(256) void k_lnffn(
    const float4* __restrict__ Apart, const float* __restrict__ Lpart,
    const float* __restrict__ inp,
    const float* __restrict__ lnw, const float* __restrict__ lnb,
    const float* __restrict__ W1, const float* __restrict__ b1,
    const float* __restrict__ Wq2, const float* __restrict__ bq2,
    const float* __restrict__ Wk2, const float* __restrict__ bk2,
    float* __restrict__ outp, float* __restrict__ Q2, float* __restrict__ K2T)
{
    const int r = blockIdx.x * 256 + threadIdx.x;
    const int b = r >> 10, s = r & 1023;

    float y[NHID];
    float mu = 0.f;
    #pragma unroll
    for (int h = 0; h < NH; ++h) {
        const size_t base = ((size_t)(b * NH + h) << 10) + s;
        float4 a  = Apart[base];
        float  ll = Lpart[base];
        #pragma unroll
        for (int c = 1; c < 4; ++c) {
            float4 t = Apart[base + (size_t)c * CHUNK_STRIDE];
            a.x += t.x; a.y += t.y; a.z += t.z; a.w += t.w;
            ll += Lpart[base + (size_t)c * CHUNK_STRIDE];
        }
        const float inv = 1.f / ll;
        y[4 * h + 0] = a.x * inv; y[4 * h + 1] = a.y * inv;
        y[4 * h + 2] = a.z * inv; y[4 * h + 3] = a.w * inv;
        mu += (a.x + a.y + a.z + a.w) * inv;
    }
    mu *= (1.f / NHID);
    float var = 0.f;
    #pragma unroll
    for (int j = 0; j < NHID; ++j) { float d = y[j] - mu; var += d * d; }
    var *= (1.f / NHID);
    const float rstd = rsqrtf(var + 1e-5f);
    #pragma unroll
    for (int j = 0; j < NHID; ++j) y[j] = (y[j] - mu) * rstd * lnw[j] + lnb[j];

    float o[NIN];
    #pragma unroll
    for (int i = 0; i < NIN; ++i) {
        float a = b1[i];
        #pragma unroll
        for (int j = 0; j < NHID; ++j) a += y[j] * W1[j * NIN + i];
        o[i] = fmaxf(a, 0.f) + inp[r * NIN + i];
        outp[r * NIN + i] = o[i];
    }

    const float rs7l2e = 0.3779644730092272f * 1.4426950408889634f;  // (1/sqrt7)*log2e
    float* K2Tb = K2T + ((size_t)b * NHID) * SS + s;
    float4* Q2r = (float4*)Q2 + (size_t)r * 7;
    #pragma unroll
    for (int j4 = 0; j4 < 7; ++j4) {
        float qq[4];
        #pragma unroll
        for (int c = 0; c < 4; ++c) {
            int j = 4 * j4 + c;
            float aq = bq2[j], ak = bk2[j];
            #pragma unroll
            for (int i = 0; i < NIN; ++i) {
                aq += o[i] * Wq2[i * NHID + j];
                ak += o[i] * Wk2[i * NHID + j];
            }
            qq[c] = aq * rs7l2e;
            K2Tb[(size_t)j * SS] = ak;      // coalesced per-j
        }
        Q2r[j4] = make_float4(qq[0], qq[1], qq[2], qq[3]);
    }
}

// ---------------------------------------------------------------------------
// Kernel 4: attention 2 weights. Wave-autonomous, 4 rows/wave; dynamic
// 28-dim loop (q via LDS scalar broadcast) + __launch_bounds__(256,4).
// Packed accumulators (8 pk_fma per r,d); per-component accumulation order
// preserved. exp2 softmax (Q2 pre-scaled by log2e in k_lnffn).
// ---------------------------------------------------------------------------
#define QR 4
__global__ __launch_bounds__(256, 4) void k_attn2(
    const float* __restrict__ Q2, const float* __restrict__ K2T,
    float* __restrict__ out2)
{
    __shared__ float q2s[16 * NHID];   // 1792 B

    const int tid  = threadIdx.x;
    const int lane = tid & 63;
    const int wid  = tid >> 6;
    const int row0 = blockIdx.x * 16;          // global row = b*1024 + s
    const int b    = row0 >> 10;

    if (tid < 112) ((float4*)q2s)[tid] = ((const float4*)Q2)[(size_t)row0 * 7 + tid];
    __syncthreads();

    const float*  qw  = q2s + wid * QR * NHID;              // this wave's 4 rows
    const float4* K2b = (const float4*)(K2T + (size_t)b * NHID * SS);  // [28][256] f4

    v2f plo[4][QR], phi[4][QR];    // [col-block][row]: 64 VGPRs total
    #pragma unroll
    for (int cb = 0; cb < 4; ++cb)
        #pragma unroll
        for (int r = 0; r < QR; ++r) { plo[cb][r] = splat2(0.f); phi[cb][r] = splat2(0.f); }

    #pragma unroll 2
    for (int d = 0; d < NHID; ++d) {
        const float4 kt0 = K2b[d * 256 +       lane];
        const float4 kt1 = K2b[d * 256 +  64 + lane];
        const float4 kt2 = K2b[d * 256 + 128 + lane];
        const float4 kt3 = K2b[d * 256 + 192 + lane];
        const v2f k0l = lo2(kt0), k0h = hi2(kt0);
        const v2f k1l = lo2(kt1), k1h = hi2(kt1);
        const v2f k2l = lo2(kt2), k2h = hi2(kt2);
        const v2f k3l = lo2(kt3), k3h = hi2(kt3);
        #pragma unroll
        for (int r = 0; r < QR; ++r) {
            const v2f qd2 = splat2(qw[r * NHID + d]);  // LDS scalar broadcast
            plo[0][r] = pkfma(qd2, k0l, plo[0][r]); phi[0][r] = pkfma(qd2, k0h, phi[0][r]);
            plo[1][r] = pkfma(qd2, k1l, plo[1][r]); phi[1][r] = pkfma(qd2, k1h, phi[1][r]);
            plo[2][r] = pkfma(qd2, k2l, plo[2][r]); phi[2][r] = pkfma(qd2, k2h, phi[2][r]);
            plo[3][r] = pkfma(qd2, k3l, plo[3][r]); phi[3][r] = pkfma(qd2, k3h, phi[3][r]);
        }
    }

    #pragma unroll
    for (int r = 0; r < QR; ++r) {
        #pragma unroll
        for (int cb = 0; cb < 4; ++cb) {
            plo[cb][r].x = EXP2F(plo[cb][r].x); plo[cb][r].y = EXP2F(plo[cb][r].y);
            phi[cb][r].x = EXP2F(phi[cb][r].x); phi[cb][r].y = EXP2F(phi[cb][r].y);
        }
        // same left-assoc chain order as before (lo.x, lo.y, hi.x, hi.y per cb)
        float sum = plo[0][r].x + plo[0][r].y + phi[0][r].x + phi[0][r].y
                  + plo[1][r].x + plo[1][r].y + phi[1][r].x + phi[1][r].y
                  + plo[2][r].x + plo[2][r].y + phi[2][r].x + phi[2][r].y
                  + plo[3][r].x + plo[3][r].y + phi[3][r].x + phi[3][r].y;
        #pragma unroll
        for (int off = 1; off < 64; off <<= 1) sum += __shfl_xor(sum, off);
        const float iv = 1.f / sum;
        float4* orow = (float4*)(out2 + ((size_t)row0 + wid * QR + r) * SS);
        #pragma unroll
        for (int cb = 0; cb < 4; ++cb)
            orow[cb * 64 + lane] = make_float4(plo[cb][r].x * iv, plo[cb][r].y * iv,
                                               phi[cb][r].x * iv, phi[cb][r].y * iv);
    }
}

// ---------------------------------------------------------------------------
extern "C" void kernel_launch(void* const* d_in, const int* in_sizes, int n_in,
                              void* d_out, int out_size, void* d_ws, size_t ws_size,
                              hipStream_t stream) {
    const float* inp = (const float*)d_in[0];
    const float* Wq  = (const float*)d_in[1];
    const float* bq  = (const float*)d_in[2];
    const float* Wk  = (const float*)d_in[3];
    const float* bk  = (const float*)d_in[4];
    const float* Wv  = (const float*)d_in[5];
    const float* bv  = (const float*)d_in[6];
    const float* lnw = (const float*)d_in[7];
    const float* lnb = (const float*)d_in[8];
    const float* W1  = (const float*)d_in[9];
    const float* b1  = (const float*)d_in[10];
    const float* Wq2 = (const float*)d_in[11];
    const float* bq2 = (const float*)d_in[12];
    const float* Wk2 = (const float*)d_in[13];
    const float* bk2 = (const float*)d_in[14];

    float* out0 = (float*)d_out;                 // [16,1024,7]
    float* out2 = out0 + ROWS * NIN;             // [16,1024,1024]

    // Split-K partials live in the out2 region (16.7M floats); k_attn2
    // overwrites it afterwards. Apart: 458752 float4 (=4*QKV_ELEMS floats),
    // Lpart: 458752 floats -> 2.29M floats total, fits easily.
    float4* Apart = (float4*)out2;
    float*  Lpart = out2 + (size_t)4 * QKV_ELEMS;

    float* ws = (float*)d_ws;
    float* Q2  = ws;
    float* K2T = ws + (size_t)QKV_ELEMS;         // [B,28,S]

    k_attn1<<<BB * NH * 16, 512, 0, stream>>>(inp, Wq, bq, Wk, bk, Wv, bv,
                                              Apart, Lpart);
    k_lnffn<<<ROWS / 256, 256, 0, stream>>>(Apart, Lpart, inp, lnw, lnb, W1, b1,
                                            Wq2, bq2, Wk2, bk2, out0, Q2, K2T);
    k_attn2<<<ROWS / 16, 256, 0, stream>>>(Q2, K2T, out2);
}